// Round 3
// baseline (487.523 us; speedup 1.0000x reference)
//
#include <hip/hip_runtime.h>
#include <hip/hip_bf16.h>
#include <stdint.h>

#define NPTS 16384
#define CDIM 256
#define HEADS 8
#define KNBR 8
#define HIDD 512
#define OUTD 64
#define NEMB 64
#define RHIDD 16

typedef _Float16 half8 __attribute__((ext_vector_type(8)));
typedef float f32x4 __attribute__((ext_vector_type(4)));

__device__ __forceinline__ float gelu_tanh(float v) {
    float v3 = v * v * v;
    return 0.5f * v * (1.0f + tanhf(0.79788456080286535588f * (v + 0.044715f * v3)));
}

__device__ __forceinline__ void gload16(const void* g, void* l) {
    __builtin_amdgcn_global_load_lds((const __attribute__((address_space(1))) void*)g,
                                     (__attribute__((address_space(3))) void*)l, 16, 0, 0);
}

// ---------------------------------------------------------------------------
// Split-fp16 MFMA GEMM, 128x128 tile, 4 waves, 16x16x32 f16 MFMA,
// 3-term (AhiBhi + AhiBlo + AloBhi) over K' = 3*Kpad -> fp32-grade accuracy.
// LDS XOR-swizzled (T2); global_load_lds with pre-swizzled source (rule #21).
// EPI 0: fp32 store (ldc)
// EPI 1: +res(x), DynTanh1 -> split h1s (stride 512); cols<64 also write the
//        h2 tail (x[:, :20] DynTanh2 + zero pad) into aux (=h2s, stride 1152)
// EPI 2: gelu(+bias) then DynTanh2 -> split h2s (stride 1152)
// EPI 3: tanh(gelu(+bias)) -> fp32, cols<64 (ld OUTD)
// ---------------------------------------------------------------------------
template <int EPI>
__launch_bounds__(256)
__global__ void gemm_split(const _Float16* __restrict__ A2, const _Float16* __restrict__ B2,
                           int Kpad, int KT,
                           void* __restrict__ Cout, int ldc,
                           const float* __restrict__ bias,
                           const float* __restrict__ res,
                           const float* __restrict__ alphap,
                           const float* __restrict__ gamma,
                           const float* __restrict__ beta,
                           const float* __restrict__ a2p,
                           const float* __restrict__ g2,
                           const float* __restrict__ b2,
                           void* __restrict__ aux) {
    __shared__ __align__(16) char lds[32768];

    const int tid = threadIdx.x;
    const int l = tid & 63, w = tid >> 6;
    const int g = l >> 4, r = l & 15;
    const int wr = w >> 1, wc = w & 1;
    const int m0 = blockIdx.y * 128;
    const int n0 = blockIdx.x * 128;
    const int ldA = 2 * Kpad;
    const int srow = l >> 3;
    const int scol = ((l & 7) ^ srow) << 3;
    const int swz = (r & 7) << 4;
    const int aBase = (wr * 64 + r) * 128;
    const int bBase = 16384 + (wc * 64 + r) * 128;

    f32x4 acc[4][4] = {};

    for (int kt = 0; kt < KT; ++kt) {
        int k0 = kt * 64;
        int term = (k0 >= Kpad) ? ((k0 >= 2 * Kpad) ? 2 : 1) : 0;
        int kk0 = k0 - term * Kpad;
        int srcA = (term < 2) ? kk0 : (Kpad + kk0);
        int srcB = (term == 1) ? (Kpad + kk0) : kk0;
        const _Float16* aS = A2 + (size_t)m0 * ldA + srcA + scol;
        const _Float16* bS = B2 + (size_t)n0 * ldA + srcB + scol;
        #pragma unroll
        for (int cc = 0; cc < 4; ++cc) {
            int ch = w * 4 + cc;
            int row = ch * 8 + srow;
            gload16(aS + (size_t)row * ldA, lds + ch * 1024);
            gload16(bS + (size_t)row * ldA, lds + 16384 + ch * 1024);
        }
        __syncthreads();
        #pragma unroll
        for (int kb = 0; kb < 2; ++kb) {
            int ko = ((kb << 6) | (g << 4)) ^ swz;
            half8 af[4], bf[4];
            #pragma unroll
            for (int i = 0; i < 4; ++i) af[i] = *(const half8*)(lds + aBase + i * 2048 + ko);
            #pragma unroll
            for (int j = 0; j < 4; ++j) bf[j] = *(const half8*)(lds + bBase + j * 2048 + ko);
            #pragma unroll
            for (int i = 0; i < 4; ++i)
                #pragma unroll
                for (int j = 0; j < 4; ++j)
                    acc[i][j] = __builtin_amdgcn_mfma_f32_16x16x32_f16(af[i], bf[j], acc[i][j], 0, 0, 0);
        }
        __syncthreads();
    }

    const float alp = (EPI == 1 || EPI == 2) ? alphap[0] : 0.f;
    #pragma unroll
    for (int i = 0; i < 4; ++i) {
        #pragma unroll
        for (int j = 0; j < 4; ++j) {
            const int gcol = n0 + wc * 64 + j * 16 + r;
            #pragma unroll
            for (int q = 0; q < 4; ++q) {
                const int row = m0 + wr * 64 + i * 16 + g * 4 + q;
                float v = acc[i][j][q];
                if (EPI == 0) {
                    ((float*)Cout)[(size_t)row * ldc + gcol] = v;
                } else if (EPI == 1) {
                    v += res[(size_t)row * CDIM + gcol];
                    v = tanhf(alp * v) * gamma[gcol] + beta[gcol];
                    _Float16 hi = (_Float16)v;
                    _Float16 lo = (_Float16)(v - (float)hi);
                    _Float16* H = (_Float16*)Cout;
                    H[(size_t)row * 512 + gcol] = hi;
                    H[(size_t)row * 512 + 256 + gcol] = lo;
                    if (gcol < 64) {
                        int tc = 512 + gcol;
                        float tv = 0.f;
                        if (gcol < 20)
                            tv = tanhf(a2p[0] * res[(size_t)row * CDIM + gcol]) * g2[tc] + b2[tc];
                        _Float16 thi = (_Float16)tv;
                        _Float16 tlo = (_Float16)(tv - (float)thi);
                        _Float16* T = (_Float16*)aux;
                        T[(size_t)row * 1152 + tc] = thi;
                        T[(size_t)row * 1152 + 576 + tc] = tlo;
                    }
                } else if (EPI == 2) {
                    v = gelu_tanh(v + bias[gcol]);
                    v = tanhf(alp * v) * gamma[gcol] + beta[gcol];
                    _Float16 hi = (_Float16)v;
                    _Float16 lo = (_Float16)(v - (float)hi);
                    _Float16* H = (_Float16*)Cout;
                    H[(size_t)row * 1152 + gcol] = hi;
                    H[(size_t)row * 1152 + 576 + gcol] = lo;
                } else {
                    if (gcol < OUTD) {
                        v = tanhf(gelu_tanh(v + bias[gcol]));
                        ((float*)Cout)[(size_t)row * OUTD + gcol] = v;
                    }
                }
            }
        }
    }
}

// ---------------------------------------------------------------------------
// x -> split fp16 [hi|lo] (grid-stride)
// ---------------------------------------------------------------------------
__global__ void x_split(const float* __restrict__ x, _Float16* __restrict__ x2) {
    for (int idx = blockIdx.x * 256 + threadIdx.x; idx < NPTS * CDIM; idx += gridDim.x * 256) {
        int n = idx >> 8, cc = idx & 255;
        float v = x[idx];
        _Float16 hi = (_Float16)v, lo = (_Float16)(v - (float)hi);
        x2[(size_t)n * 512 + cc] = hi;
        x2[(size_t)n * 512 + 256 + cc] = lo;
    }
}

// ---------------------------------------------------------------------------
// merged weight prep: wqkv (1536x256), WoT (256x576), WlinT (512x256),
// WoutT (128x576) -> split [hi|lo]
// ---------------------------------------------------------------------------
#define S1 393216
#define S2 147456
#define S3 131072
#define S4 73728
__global__ void prep_w(const float* __restrict__ Wq, const float* __restrict__ Wk,
                       const float* __restrict__ Wv, const float* __restrict__ Wo,
                       const float* __restrict__ Wlin, const float* __restrict__ Wout,
                       _Float16* __restrict__ wqkv2, _Float16* __restrict__ wo2,
                       _Float16* __restrict__ wlin2, _Float16* __restrict__ wout2) {
    for (int idx = blockIdx.x * 256 + threadIdx.x; idx < S1 + S2 + S3 + S4;
         idx += gridDim.x * 256) {
        float v; _Float16* dst; size_t o0, o1;
        if (idx < S1) {
            int j = idx >> 8, k = idx & 255;
            int jm = j & 511;
            const float* W = (j < 512) ? Wq : (j < 1024) ? Wk : Wv;
            v = W[(size_t)k * 512 + jm];
            dst = wqkv2; o0 = (size_t)j * 512 + k; o1 = o0 + 256;
        } else if (idx < S1 + S2) {
            int t = idx - S1;
            int j = t / 576, k = t - j * 576;
            v = (k < 520) ? Wo[(size_t)k * 256 + j] : 0.f;
            dst = wo2; o0 = (size_t)j * 1152 + k; o1 = o0 + 576;
        } else if (idx < S1 + S2 + S3) {
            int t = idx - S1 - S2;
            int j = t >> 8, k = t & 255;
            v = Wlin[(size_t)k * 512 + j];
            dst = wlin2; o0 = (size_t)j * 512 + k; o1 = o0 + 256;
        } else {
            int t = idx - S1 - S2 - S3;
            int j = t / 576, k = t - j * 576;
            v = (j < 64 && k < 532) ? Wout[(size_t)k * 64 + j] : 0.f;
            dst = wout2; o0 = (size_t)j * 1152 + k; o1 = o0 + 576;
        }
        _Float16 hi = (_Float16)v, lo = (_Float16)(v - (float)hi);
        dst[o0] = hi; dst[o1] = lo;
    }
}

// ---------------------------------------------------------------------------
// gate: one wave per node; lane = h*8+c; chunk dot + shuffle reduce over c
// ---------------------------------------------------------------------------
__launch_bounds__(256)
__global__ void gate_kernel(const float* __restrict__ x, const float* __restrict__ w_gate,
                            float* __restrict__ G) {
    const int tid = threadIdx.x;
    const int w = tid >> 6, lane = tid & 63;
    const int n = blockIdx.x * 4 + w;
    const int h = lane >> 3, c = lane & 7;
    const float* xr = x + (size_t)n * CDIM + c * 32;
    const float* wg = w_gate + (size_t)c * 32 * 8 + h;
    float s = 0.f;
    #pragma unroll
    for (int i = 0; i < 32; ++i) s += xr[i] * wg[i * 8];
    s += __shfl_xor(s, 1, 64);
    s += __shfl_xor(s, 2, 64);
    s += __shfl_xor(s, 4, 64);
    if (c == 0) G[(size_t)n * 8 + h] = s;
}

// ---------------------------------------------------------------------------
// Attention: one wave per node. All gathers (K, then V+G) issued before the
// softmax VALU phase so latency hides under compute. Per-wave LDS only
// (wave_barrier, no __syncthreads).
// ---------------------------------------------------------------------------
__launch_bounds__(256)
__global__ void attn_kernel(const float* __restrict__ QKV, const float* __restrict__ G,
                            const float* __restrict__ coors, const int* __restrict__ nbr,
                            const float* __restrict__ Wr1, const float* __restrict__ br1,
                            const float* __restrict__ Wr2, const float* __restrict__ br2,
                            _Float16* __restrict__ att2) {
    __shared__ float unitL[4][8][3];
    __shared__ float distL[4][8];
    __shared__ float radH[4][8][16];

    const int tid = threadIdx.x;
    const int w = tid >> 6;
    const int lane = tid & 63;
    const int n = blockIdx.x * 4 + w;
    const int h = lane >> 3;
    const int c = lane & 7;

    int jreg[KNBR];
    #pragma unroll
    for (int k = 0; k < KNBR; ++k) jreg[k] = nbr[(size_t)n * KNBR + k];

    // ---- issue Q + all K gathers ----
    const float4* qp = (const float4*)(QKV + (size_t)n * 1536 + lane * 8);
    float4 q0 = qp[0], q1 = qp[1];
    float4 kr[KNBR][2];
    #pragma unroll
    for (int k = 0; k < KNBR; ++k) {
        const float4* kp = (const float4*)(QKV + (size_t)jreg[k] * 1536 + 512 + lane * 8);
        kr[k][0] = kp[0];
        kr[k][1] = kp[1];
    }

    // dist/unit (lanes 0..7)
    if (lane < KNBR) {
        int jj = jreg[lane];
        float rx = coors[(size_t)jj * 3 + 0] - coors[(size_t)n * 3 + 0];
        float ry = coors[(size_t)jj * 3 + 1] - coors[(size_t)n * 3 + 1];
        float rz = coors[(size_t)jj * 3 + 2] - coors[(size_t)n * 3 + 2];
        float d = sqrtf(rx * rx + ry * ry + rz * rz + 1e-8f);
        float inv = 1.0f / d;
        distL[w][lane] = d;
        unitL[w][lane][0] = rx * inv;
        unitL[w][lane][1] = ry * inv;
        unitL[w][lane][2] = rz * inv;
    }
    __builtin_amdgcn_wave_barrier();

    // QK dots (consume kr)
    float p[KNBR];
    #pragma unroll
    for (int k = 0; k < KNBR; ++k) {
        float4 k0 = kr[k][0], k1 = kr[k][1];
        p[k] = q0.x * k0.x + q0.y * k0.y + q0.z * k0.z + q0.w * k0.w
             + q1.x * k1.x + q1.y * k1.y + q1.z * k1.z + q1.w * k1.w;
    }

    // ---- issue all V + G gathers (consumed after softmax) ----
    float4 vr[KNBR][2];
    float gk[KNBR];
    #pragma unroll
    for (int k = 0; k < KNBR; ++k) {
        const float4* vp = (const float4*)(QKV + (size_t)jreg[k] * 1536 + 1024 + lane * 8);
        vr[k][0] = vp[0];
        vr[k][1] = vp[1];
        gk[k] = G[(size_t)jreg[k] * 8 + h];
    }

    #pragma unroll
    for (int m = 1; m <= 4; m <<= 1) {
        #pragma unroll
        for (int k = 0; k < KNBR; ++k) p[k] += __shfl_xor(p[k], m, 64);
    }

    // radial hidden (per-wave, 2 (k,i) pairs per lane)
    #pragma unroll
    for (int rr = 0; rr < 2; ++rr) {
        int idx = lane + rr * 64;
        int k = idx >> 4, i = idx & 15;
        float hv = distL[w][k] * Wr1[i] + br1[i];
        radH[w][k][i] = gelu_tanh(hv);
    }
    __builtin_amdgcn_wave_barrier();

    float wr2h[RHIDD];
    #pragma unroll
    for (int i = 0; i < RHIDD; ++i) wr2h[i] = Wr2[i * HEADS + h];

    float lg[KNBR];
    float b2v = br2[h];
    #pragma unroll
    for (int k = 0; k < KNBR; ++k) {
        float rad = b2v;
        #pragma unroll
        for (int i = 0; i < RHIDD; ++i) rad += radH[w][k][i] * wr2h[i];
        lg[k] = p[k] * 0.125f + rad;
        if (!(distL[w][k] <= 10.0f)) lg[k] = -1e9f;
    }
    float mx = lg[0];
    #pragma unroll
    for (int k = 1; k < KNBR; ++k) mx = fmaxf(mx, lg[k]);
    float a[KNBR];
    float s = 0.f;
    #pragma unroll
    for (int k = 0; k < KNBR; ++k) { a[k] = expf(lg[k] - mx); s += a[k]; }
    float is = 1.0f / s;
    #pragma unroll
    for (int k = 0; k < KNBR; ++k) a[k] *= is;

    // degree-1 (consume gk + unitL)
    float vx = 0.f, vy = 0.f, vz = 0.f;
    #pragma unroll
    for (int k = 0; k < KNBR; ++k) {
        float ag = a[k] * gk[k];
        vx += ag * unitL[w][k][0];
        vy += ag * unitL[w][k][1];
        vz += ag * unitL[w][k][2];
    }
    float vn = sqrtf(vx * vx + vy * vy + vz * vz + 1e-8f);

    // out0 (consume vr)
    float4 o0 = {0.f, 0.f, 0.f, 0.f}, o1 = {0.f, 0.f, 0.f, 0.f};
    #pragma unroll
    for (int k = 0; k < KNBR; ++k) {
        float4 v0 = vr[k][0], v1 = vr[k][1];
        float ak = a[k];
        o0.x += ak * v0.x; o0.y += ak * v0.y; o0.z += ak * v0.z; o0.w += ak * v0.w;
        o1.x += ak * v1.x; o1.y += ak * v1.y; o1.z += ak * v1.z; o1.w += ak * v1.w;
    }

    float ov[8] = {o0.x, o0.y, o0.z, o0.w, o1.x, o1.y, o1.z, o1.w};
    half8 hi8, lo8;
    #pragma unroll
    for (int t = 0; t < 8; ++t) {
        _Float16 hi = (_Float16)ov[t];
        hi8[t] = hi;
        lo8[t] = (_Float16)(ov[t] - (float)hi);
    }
    *(half8*)(att2 + (size_t)n * 1152 + lane * 8) = hi8;
    *(half8*)(att2 + (size_t)n * 1152 + 576 + lane * 8) = lo8;
    if (c == 0) {
        _Float16 hi = (_Float16)vn, lo = (_Float16)(vn - (float)hi);
        att2[(size_t)n * 1152 + 512 + h] = hi;
        att2[(size_t)n * 1152 + 576 + 512 + h] = lo;
    }
    if (lane < 56) {
        att2[(size_t)n * 1152 + 520 + lane] = (_Float16)0.f;
        att2[(size_t)n * 1152 + 1096 + lane] = (_Float16)0.f;
    }
}

// ---------------------------------------------------------------------------
// VQ
// ---------------------------------------------------------------------------
__launch_bounds__(256)
__global__ void vq_kernel(const float* __restrict__ z, const float* __restrict__ cb,
                          float* __restrict__ out, float* __restrict__ partials) {
    __shared__ float cbL[NEMB][65];
    __shared__ float zL[4][OUTD];
    __shared__ float psum[4];

    const int tid = threadIdx.x;
    for (int i = tid; i < NEMB * OUTD / 4; i += 256) {
        float4 v = ((const float4*)cb)[i];
        int e = (i * 4) >> 6;
        int c0 = (i * 4) & 63;
        cbL[e][c0 + 0] = v.x; cbL[e][c0 + 1] = v.y;
        cbL[e][c0 + 2] = v.z; cbL[e][c0 + 3] = v.w;
    }
    const int w = tid >> 6;
    const int lane = tid & 63;
    const int n = blockIdx.x * 4 + w;
    zL[w][lane] = z[(size_t)n * OUTD + lane];
    __syncthreads();

    float dot = 0.f, cc = 0.f;
    #pragma unroll
    for (int i = 0; i < OUTD; ++i) {
        float cv = cbL[lane][i];
        dot += zL[w][i] * cv;
        cc += cv * cv;
    }
    float best = cc - 2.f * dot;
    int bidx = lane;
    #pragma unroll
    for (int m = 1; m < 64; m <<= 1) {
        float ob = __shfl_xor(best, m, 64);
        int oi = __shfl_xor(bidx, m, 64);
        if (ob < best || (ob == best && oi < bidx)) { best = ob; bidx = oi; }
    }
    float zq = cbL[bidx][lane];
    out[(size_t)n * OUTD + lane] = zq;
    float diff = zL[w][lane] - zq;
    float sq = diff * diff;
    #pragma unroll
    for (int m = 1; m < 64; m <<= 1) sq += __shfl_xor(sq, m, 64);
    if (lane == 0) psum[w] = sq;
    __syncthreads();
    if (tid == 0) partials[blockIdx.x] = psum[0] + psum[1] + psum[2] + psum[3];
}

__global__ void vq_reduce(const float* __restrict__ partials, float* __restrict__ out) {
    __shared__ float s[256];
    int tid = threadIdx.x;
    float acc = 0.f;
    for (int i = tid; i < NPTS / 4; i += 256) acc += partials[i];
    s[tid] = acc;
    __syncthreads();
    for (int st = 128; st > 0; st >>= 1) {
        if (tid < st) s[tid] += s[tid + st];
        __syncthreads();
    }
    if (tid == 0) out[0] = 0.25f * s[0] / ((float)NPTS * (float)OUTD);
}

// ---------------------------------------------------------------------------
extern "C" void kernel_launch(void* const* d_in, const int* in_sizes, int n_in,
                              void* d_out, int out_size, void* d_ws, size_t ws_size,
                              hipStream_t stream) {
    const float* x      = (const float*)d_in[0];
    const float* coors  = (const float*)d_in[1];
    const int*   nbr    = (const int*)  d_in[2];
    const float* Wq     = (const float*)d_in[3];
    const float* Wk     = (const float*)d_in[4];
    const float* Wv     = (const float*)d_in[5];
    const float* w_gate = (const float*)d_in[6];
    const float* Wr1    = (const float*)d_in[7];
    const float* br1    = (const float*)d_in[8];
    const float* Wr2    = (const float*)d_in[9];
    const float* br2    = (const float*)d_in[10];
    const float* Wo     = (const float*)d_in[11];
    const float* alpha1 = (const float*)d_in[12];
    const float* gamma1 = (const float*)d_in[13];
    const float* beta1  = (const float*)d_in[14];
    const float* Wlin   = (const float*)d_in[15];
    const float* blin   = (const float*)d_in[16];
    const float* alpha2 = (const float*)d_in[17];
    const float* gamma2 = (const float*)d_in[18];
    const float* beta2  = (const float*)d_in[19];
    const float* Wout   = (const float*)d_in[20];
    const float* bout   = (const float*)d_in[21];
    const float* cb     = (const float*)d_in[22];

    char* wsb = (char*)d_ws;
    float*    QKV   = (float*)   (wsb + 0);          // 100.66 MB, dead after attn
    _Float16* att2  = (_Float16*)(wsb + 100663296);  // 37.75 MB, dead after Wo gemm
    _Float16* x2    = (_Float16*)(wsb + 138412032);  // 16.78 MB, dead after QKV gemm
    _Float16* wqkv2 = (_Float16*)(wsb + 155189248);
    _Float16* wo2   = (_Float16*)(wsb + 156762112);
    _Float16* wlin2 = (_Float16*)(wsb + 157351936);
    _Float16* wout2 = (_Float16*)(wsb + 157876224);
    float*    G     = (float*)   (wsb + 158171136);
    float*    part  = (float*)   (wsb + 158695424);  // ends 158711808
    // aliases inside dead QKV region:
    _Float16* h1s   = (_Float16*)(wsb + 0);          // 16.78 MB (after attn)
    _Float16* h2s   = (_Float16*)(wsb + 20299776);   // 37.75 MB (after attn)
    float*    z     = (float*)   (wsb + 62914560);   // 4.19 MB

    float* outZ    = (float*)d_out;
    float* outLoss = outZ + (size_t)NPTS * OUTD;

    dim3 blk(256);

    // prep
    x_split<<<dim3(2048), blk, 0, stream>>>(x, x2);
    prep_w <<<dim3(2048), blk, 0, stream>>>(Wq, Wk, Wv, Wo, Wlin, Wout,
                                            wqkv2, wo2, wlin2, wout2);
    gate_kernel<<<dim3(NPTS / 4), blk, 0, stream>>>(x, w_gate, G);

    // QKV = x @ [Wq|Wk|Wv]
    gemm_split<0><<<dim3(12, 128), blk, 0, stream>>>(x2, wqkv2, 256, 12, QKV, 1536,
        nullptr, nullptr, nullptr, nullptr, nullptr, nullptr, nullptr, nullptr, nullptr);
    // attention
    attn_kernel<<<dim3(NPTS / 4), blk, 0, stream>>>(QKV, G, coors, nbr, Wr1, br1, Wr2, br2, att2);
    // h1 = DynTanh1(x + att@Wo) -> split; also writes h2 tail cols (x[:, :20])
    gemm_split<1><<<dim3(2, 128), blk, 0, stream>>>(att2, wo2, 576, 27, h1s, 0,
        nullptr, x, alpha1, gamma1, beta1, alpha2, gamma2, beta2, h2s);
    // h2[:, :512] = DynTanh2(gelu(h1@Wlin + blin)) -> split
    gemm_split<2><<<dim3(4, 128), blk, 0, stream>>>(h1s, wlin2, 256, 12, h2s, 0,
        blin, nullptr, alpha2, gamma2, beta2, nullptr, nullptr, nullptr, nullptr);
    // z = tanh(gelu(h2@Wout + bout))
    gemm_split<3><<<dim3(1, 128), blk, 0, stream>>>(h2s, wout2, 576, 27, z, 64,
        bout, nullptr, nullptr, nullptr, nullptr, nullptr, nullptr, nullptr, nullptr);
    // VQ
    vq_kernel<<<dim3(NPTS / 4), blk, 0, stream>>>(z, cb, outZ, part);
    vq_reduce<<<dim3(1), blk, 0, stream>>>(part, outLoss);
}

// Round 5
// 426.803 us; speedup vs baseline: 1.1423x; 1.1423x over previous
//
#include <hip/hip_runtime.h>
#include <hip/hip_bf16.h>
#include <stdint.h>

#define NPTS 16384
#define CDIM 256
#define HEADS 8
#define KNBR 8
#define HIDD 512
#define OUTD 64
#define NEMB 64
#define RHIDD 16

typedef _Float16 half8 __attribute__((ext_vector_type(8)));
typedef float f32x4 __attribute__((ext_vector_type(4)));

__device__ __forceinline__ float gelu_tanh(float v) {
    float v3 = v * v * v;
    return 0.5f * v * (1.0f + tanhf(0.79788456080286535588f * (v + 0.044715f * v3)));
}

__device__ __forceinline__ void gload16(const void* g, void* l) {
    __builtin_amdgcn_global_load_lds((const __attribute__((address_space(1))) void*)g,
                                     (__attribute__((address_space(3))) void*)l, 16, 0, 0);
}

// ---------------------------------------------------------------------------
// Split-fp16 MFMA GEMM, 128x128 tile, 4 waves, 16x16x32 f16 MFMA,
// 3-term (AhiBhi + AhiBlo + AloBhi) over K' = 3*Kpad -> fp32-grade accuracy.
// LDS XOR-swizzled (T2); global_load_lds linear dest + pre-swizzled source.
// EPI 0: QKV+gate: cols<1536 -> fp32 QKV (ld 1536); cols 1536..1543 -> G[N,8]
// EPI 1: +res(x), DynTanh1 -> split h1s (stride 512); cols<64 also write the
//        h2 tail (x[:, :20] DynTanh2 + zero pad) into aux (=h2s, stride 1152)
// EPI 2: gelu(+bias) then DynTanh2 -> split h2s (stride 1152)
// ---------------------------------------------------------------------------
template <int EPI>
__launch_bounds__(256)
__global__ void gemm_split(const _Float16* __restrict__ A2, const _Float16* __restrict__ B2,
                           int Kpad, int KT,
                           void* __restrict__ Cout, int ldc,
                           const float* __restrict__ bias,
                           const float* __restrict__ res,
                           const float* __restrict__ alphap,
                           const float* __restrict__ gamma,
                           const float* __restrict__ beta,
                           const float* __restrict__ a2p,
                           const float* __restrict__ g2,
                           const float* __restrict__ b2,
                           void* __restrict__ aux) {
    __shared__ __align__(16) char lds[32768];

    const int tid = threadIdx.x;
    const int l = tid & 63, w = tid >> 6;
    const int g = l >> 4, r = l & 15;
    const int wr = w >> 1, wc = w & 1;
    const int m0 = blockIdx.y * 128;
    const int n0 = blockIdx.x * 128;
    const int ldA = 2 * Kpad;
    const int srow = l >> 3;
    const int scol = ((l & 7) ^ srow) << 3;
    const int swz = (r & 7) << 4;
    const int aBase = (wr * 64 + r) * 128;
    const int bBase = 16384 + (wc * 64 + r) * 128;

    f32x4 acc[4][4] = {};

    for (int kt = 0; kt < KT; ++kt) {
        int k0 = kt * 64;
        int term = (k0 >= Kpad) ? ((k0 >= 2 * Kpad) ? 2 : 1) : 0;
        int kk0 = k0 - term * Kpad;
        int srcA = (term < 2) ? kk0 : (Kpad + kk0);
        int srcB = (term == 1) ? (Kpad + kk0) : kk0;
        const _Float16* aS = A2 + (size_t)m0 * ldA + srcA + scol;
        const _Float16* bS = B2 + (size_t)n0 * ldA + srcB + scol;
        #pragma unroll
        for (int cc = 0; cc < 4; ++cc) {
            int ch = w * 4 + cc;
            int row = ch * 8 + srow;
            gload16(aS + (size_t)row * ldA, lds + ch * 1024);
            gload16(bS + (size_t)row * ldA, lds + 16384 + ch * 1024);
        }
        __syncthreads();
        #pragma unroll
        for (int kb = 0; kb < 2; ++kb) {
            int ko = ((kb << 6) | (g << 4)) ^ swz;
            half8 af[4], bf[4];
            #pragma unroll
            for (int i = 0; i < 4; ++i) af[i] = *(const half8*)(lds + aBase + i * 2048 + ko);
            #pragma unroll
            for (int j = 0; j < 4; ++j) bf[j] = *(const half8*)(lds + bBase + j * 2048 + ko);
            #pragma unroll
            for (int i = 0; i < 4; ++i)
                #pragma unroll
                for (int j = 0; j < 4; ++j)
                    acc[i][j] = __builtin_amdgcn_mfma_f32_16x16x32_f16(af[i], bf[j], acc[i][j], 0, 0, 0);
        }
        __syncthreads();
    }

    const float alp = (EPI == 1 || EPI == 2) ? alphap[0] : 0.f;
    #pragma unroll
    for (int i = 0; i < 4; ++i) {
        #pragma unroll
        for (int j = 0; j < 4; ++j) {
            const int gcol = n0 + wc * 64 + j * 16 + r;
            #pragma unroll
            for (int q = 0; q < 4; ++q) {
                const int row = m0 + wr * 64 + i * 16 + g * 4 + q;
                float v = acc[i][j][q];
                if (EPI == 0) {
                    if (gcol < 1536) {
                        ((float*)Cout)[(size_t)row * 1536 + gcol] = v;
                    } else if (gcol < 1544) {
                        ((float*)aux)[(size_t)row * 8 + (gcol - 1536)] = v;
                    }
                } else if (EPI == 1) {
                    v += res[(size_t)row * CDIM + gcol];
                    v = tanhf(alp * v) * gamma[gcol] + beta[gcol];
                    _Float16 hi = (_Float16)v;
                    _Float16 lo = (_Float16)(v - (float)hi);
                    _Float16* H = (_Float16*)Cout;
                    H[(size_t)row * 512 + gcol] = hi;
                    H[(size_t)row * 512 + 256 + gcol] = lo;
                    if (gcol < 64) {
                        int tc = 512 + gcol;
                        float tv = 0.f;
                        if (gcol < 20)
                            tv = tanhf(a2p[0] * res[(size_t)row * CDIM + gcol]) * g2[tc] + b2[tc];
                        _Float16 thi = (_Float16)tv;
                        _Float16 tlo = (_Float16)(tv - (float)thi);
                        _Float16* T = (_Float16*)aux;
                        T[(size_t)row * 1152 + tc] = thi;
                        T[(size_t)row * 1152 + 576 + tc] = tlo;
                    }
                } else if (EPI == 2) {
                    v = gelu_tanh(v + bias[gcol]);
                    v = tanhf(alp * v) * gamma[gcol] + beta[gcol];
                    _Float16 hi = (_Float16)v;
                    _Float16 lo = (_Float16)(v - (float)hi);
                    _Float16* H = (_Float16*)Cout;
                    H[(size_t)row * 1152 + gcol] = hi;
                    H[(size_t)row * 1152 + 576 + gcol] = lo;
                }
            }
        }
    }
}

// ---------------------------------------------------------------------------
// Wout GEMM (64x64 tile, 256 blocks) with fused VQ.
// z = tanh(gelu(h2 @ WoutT + bout)) kept in LDS; argmin vs codebook; writes
// zq rows to outZ and per-block squared-error partial (deterministic).
// ---------------------------------------------------------------------------
__launch_bounds__(256)
__global__ void gemm_out_vq(const _Float16* __restrict__ A2, const _Float16* __restrict__ B2,
                            const float* __restrict__ bout, const float* __restrict__ cb,
                            float* __restrict__ outZ, float* __restrict__ partials) {
    __shared__ __align__(16) char lds[34816];   // 16KB staging, then zL|cbL
    __shared__ float psum[64];
    float* zL  = (float*)lds;                   // [64][68]
    float* cbL = (float*)(lds + 17408);         // [64][68], col 64 = ||cb||^2

    const int tid = threadIdx.x;
    const int l = tid & 63, w = tid >> 6;
    const int g = l >> 4, r = l & 15;
    const int wr = w >> 1, wc = w & 1;
    const int m0 = blockIdx.x * 64;
    const int ldA = 1152;                       // 2*Kpad, Kpad=576
    const int srow = l >> 3;
    const int scol = ((l & 7) ^ srow) << 3;
    const int swz = (r & 7) << 4;
    const int aBase = (wr * 32 + r) * 128;
    const int bBase = 8192 + (wc * 32 + r) * 128;

    f32x4 acc[2][2] = {};

    for (int kt = 0; kt < 27; ++kt) {
        int k0 = kt * 64;
        int term = (k0 >= 576) ? ((k0 >= 1152) ? 2 : 1) : 0;
        int kk0 = k0 - term * 576;
        int srcA = (term < 2) ? kk0 : (576 + kk0);
        int srcB = (term == 1) ? (576 + kk0) : kk0;
        const _Float16* aS = A2 + (size_t)m0 * ldA + srcA + scol;
        const _Float16* bS = B2 + srcB + scol;
        #pragma unroll
        for (int cc = 0; cc < 2; ++cc) {
            int ch = w * 2 + cc;
            int row = ch * 8 + srow;
            gload16(aS + (size_t)row * ldA, lds + ch * 1024);
            gload16(bS + (size_t)row * ldA, lds + 8192 + ch * 1024);
        }
        __syncthreads();
        #pragma unroll
        for (int kb = 0; kb < 2; ++kb) {
            int ko = ((kb << 6) | (g << 4)) ^ swz;
            half8 af[2], bf[2];
            #pragma unroll
            for (int i = 0; i < 2; ++i) af[i] = *(const half8*)(lds + aBase + i * 2048 + ko);
            #pragma unroll
            for (int j = 0; j < 2; ++j) bf[j] = *(const half8*)(lds + bBase + j * 2048 + ko);
            #pragma unroll
            for (int i = 0; i < 2; ++i)
                #pragma unroll
                for (int j = 0; j < 2; ++j)
                    acc[i][j] = __builtin_amdgcn_mfma_f32_16x16x32_f16(af[i], bf[j], acc[i][j], 0, 0, 0);
        }
        __syncthreads();
    }

    // z -> zL (staging region is dead now)
    #pragma unroll
    for (int i = 0; i < 2; ++i) {
        #pragma unroll
        for (int j = 0; j < 2; ++j) {
            int col = wc * 32 + j * 16 + r;
            #pragma unroll
            for (int q = 0; q < 4; ++q) {
                int rl = wr * 32 + i * 16 + g * 4 + q;
                zL[rl * 68 + col] = tanhf(gelu_tanh(acc[i][j][q] + bout[col]));
            }
        }
    }
    // stage codebook
    for (int i = tid; i < NEMB * OUTD / 4; i += 256) {
        float4 v = ((const float4*)cb)[i];
        int e = (i * 4) >> 6, c0 = (i * 4) & 63;
        cbL[e * 68 + c0 + 0] = v.x; cbL[e * 68 + c0 + 1] = v.y;
        cbL[e * 68 + c0 + 2] = v.z; cbL[e * 68 + c0 + 3] = v.w;
    }
    __syncthreads();
    if (tid < 64) {
        float cc = 0.f;
        #pragma unroll
        for (int d = 0; d < 64; ++d) { float cv = cbL[tid * 68 + d]; cc += cv * cv; }
        cbL[tid * 68 + 64] = cc;
    }
    __syncthreads();

    const int row = tid >> 2, part = tid & 3;
    float best = 1e30f;
    int bidx = 0;
    for (int e = part * 16; e < part * 16 + 16; ++e) {
        float dot = 0.f;
        #pragma unroll
        for (int d = 0; d < 64; ++d) dot += zL[row * 68 + d] * cbL[e * 68 + d];
        float sc = cbL[e * 68 + 64] - 2.f * dot;
        if (sc < best) { best = sc; bidx = e; }
    }
    #pragma unroll
    for (int m = 1; m <= 2; m <<= 1) {
        float ob = __shfl_xor(best, m, 64);
        int oi = __shfl_xor(bidx, m, 64);
        if (ob < best || (ob == best && oi < bidx)) { best = ob; bidx = oi; }
    }
    const int grow = m0 + row;
    float lsum = 0.f;
    #pragma unroll
    for (int u = 0; u < 16; ++u) {
        float cv = cbL[bidx * 68 + part * 16 + u];
        outZ[(size_t)grow * 64 + part * 16 + u] = cv;
        float df = zL[row * 68 + part * 16 + u] - cv;
        lsum += df * df;
    }
    lsum += __shfl_xor(lsum, 1, 64);
    lsum += __shfl_xor(lsum, 2, 64);
    if (part == 0) psum[row] = lsum;
    __syncthreads();
    if (tid < 64) {
        float v = psum[tid];
        #pragma unroll
        for (int m = 1; m < 64; m <<= 1) v += __shfl_xor(v, m, 64);
        if (tid == 0) partials[blockIdx.x] = v;
    }
}

__global__ void vq_reduce(const float* __restrict__ partials, float* __restrict__ out) {
    __shared__ float s[256];
    int tid = threadIdx.x;
    s[tid] = partials[tid];
    __syncthreads();
    for (int st = 128; st > 0; st >>= 1) {
        if (tid < st) s[tid] += s[tid + st];
        __syncthreads();
    }
    if (tid == 0) out[0] = 0.25f * s[0] / ((float)NPTS * (float)OUTD);
}

// ---------------------------------------------------------------------------
// merged prep: x2 split, wqkv2 (incl gate cols + zero pad), wo2T, wlin2T, wout2T
// ---------------------------------------------------------------------------
#define R0 (NPTS * CDIM)
#define S1 (1664 * 256)
#define S2 (256 * 576)
#define S3 (512 * 256)
#define S4 (64 * 576)
__global__ void prep(const float* __restrict__ x,
                     const float* __restrict__ Wq, const float* __restrict__ Wk,
                     const float* __restrict__ Wv, const float* __restrict__ w_gate,
                     const float* __restrict__ Wo, const float* __restrict__ Wlin,
                     const float* __restrict__ Wout,
                     _Float16* __restrict__ x2, _Float16* __restrict__ wqkv2,
                     _Float16* __restrict__ wo2, _Float16* __restrict__ wlin2,
                     _Float16* __restrict__ wout2) {
    for (int idx = blockIdx.x * 256 + threadIdx.x; idx < R0 + S1 + S2 + S3 + S4;
         idx += gridDim.x * 256) {
        float v; _Float16* dst; size_t o0, o1;
        if (idx < R0) {
            int n = idx >> 8, cc = idx & 255;
            v = x[idx];
            dst = x2; o0 = (size_t)n * 512 + cc; o1 = o0 + 256;
        } else if (idx < R0 + S1) {
            int t = idx - R0;
            int j = t >> 8, k = t & 255;
            if (j < 1536) {
                int jm = j & 511;
                const float* W = (j < 512) ? Wq : (j < 1024) ? Wk : Wv;
                v = W[(size_t)k * 512 + jm];
            } else if (j < 1544) {
                v = w_gate[(size_t)k * 8 + (j - 1536)];
            } else {
                v = 0.f;
            }
            dst = wqkv2; o0 = (size_t)j * 512 + k; o1 = o0 + 256;
        } else if (idx < R0 + S1 + S2) {
            int t = idx - R0 - S1;
            int j = t / 576, k = t - j * 576;
            v = (k < 520) ? Wo[(size_t)k * 256 + j] : 0.f;
            dst = wo2; o0 = (size_t)j * 1152 + k; o1 = o0 + 576;
        } else if (idx < R0 + S1 + S2 + S3) {
            int t = idx - R0 - S1 - S2;
            int j = t >> 8, k = t & 255;
            v = Wlin[(size_t)k * 512 + j];
            dst = wlin2; o0 = (size_t)j * 512 + k; o1 = o0 + 256;
        } else {
            int t = idx - R0 - S1 - S2 - S3;
            int j = t / 576, k = t - j * 576;
            v = (k < 532) ? Wout[(size_t)k * 64 + j] : 0.f;
            dst = wout2; o0 = (size_t)j * 1152 + k; o1 = o0 + 576;
        }
        _Float16 hi = (_Float16)v, lo = (_Float16)(v - (float)hi);
        dst[o0] = hi; dst[o1] = lo;
    }
}

// ---------------------------------------------------------------------------
// Attention (round-2 measured-best form): one wave per node, lane = h*8+c.
// ---------------------------------------------------------------------------
__launch_bounds__(256)
__global__ void attn_kernel(const float* __restrict__ QKV, const float* __restrict__ G,
                            const float* __restrict__ coors, const int* __restrict__ nbr,
                            const float* __restrict__ Wr1, const float* __restrict__ br1,
                            const float* __restrict__ Wr2, const float* __restrict__ br2,
                            _Float16* __restrict__ att2) {
    __shared__ float unitL[4][8][3];
    __shared__ float distL[4][8];
    __shared__ float radH[4][8][16];

    const int tid = threadIdx.x;
    const int w = tid >> 6;
    const int lane = tid & 63;
    const int n = blockIdx.x * 4 + w;
    const int h = lane >> 3;
    const int c = lane & 7;

    int jreg[KNBR];
    #pragma unroll
    for (int k = 0; k < KNBR; ++k) jreg[k] = nbr[(size_t)n * KNBR + k];

    if (lane < KNBR) {
        int jj = jreg[lane];
        float rx = coors[(size_t)jj * 3 + 0] - coors[(size_t)n * 3 + 0];
        float ry = coors[(size_t)jj * 3 + 1] - coors[(size_t)n * 3 + 1];
        float rz = coors[(size_t)jj * 3 + 2] - coors[(size_t)n * 3 + 2];
        float d = sqrtf(rx * rx + ry * ry + rz * rz + 1e-8f);
        float inv = 1.0f / d;
        distL[w][lane] = d;
        unitL[w][lane][0] = rx * inv;
        unitL[w][lane][1] = ry * inv;
        unitL[w][lane][2] = rz * inv;
    }

    const float4* qp = (const float4*)(QKV + (size_t)n * 1536 + lane * 8);
    float4 q0 = qp[0], q1 = qp[1];
    float p[KNBR];
    #pragma unroll
    for (int k = 0; k < KNBR; ++k) {
        const float4* kp = (const float4*)(QKV + (size_t)jreg[k] * 1536 + 512 + lane * 8);
        float4 k0 = kp[0], k1 = kp[1];
        p[k] = q0.x * k0.x + q0.y * k0.y + q0.z * k0.z + q0.w * k0.w
             + q1.x * k1.x + q1.y * k1.y + q1.z * k1.z + q1.w * k1.w;
    }
    #pragma unroll
    for (int m = 1; m <= 4; m <<= 1) {
        #pragma unroll
        for (int k = 0; k < KNBR; ++k) p[k] += __shfl_xor(p[k], m, 64);
    }
    __syncthreads();

    #pragma unroll
    for (int rr = 0; rr < 2; ++rr) {
        int idx = lane + rr * 64;
        int k = idx >> 4, i = idx & 15;
        float hv = distL[w][k] * Wr1[i] + br1[i];
        radH[w][k][i] = gelu_tanh(hv);
    }
    __syncthreads();

    float lg[KNBR];
    float b2v = br2[h];
    #pragma unroll
    for (int k = 0; k < KNBR; ++k) {
        float rad = b2v;
        #pragma unroll
        for (int i = 0; i < RHIDD; ++i) rad += radH[w][k][i] * Wr2[i * HEADS + h];
        lg[k] = p[k] * 0.125f + rad;
        if (!(distL[w][k] <= 10.0f)) lg[k] = -1e9f;
    }
    float mx = lg[0];
    #pragma unroll
    for (int k = 1; k < KNBR; ++k) mx = fmaxf(mx, lg[k]);
    float a[KNBR];
    float s = 0.f;
    #pragma unroll
    for (int k = 0; k < KNBR; ++k) { a[k] = expf(lg[k] - mx); s += a[k]; }
    float is = 1.0f / s;
    #pragma unroll
    for (int k = 0; k < KNBR; ++k) a[k] *= is;

    float vx = 0.f, vy = 0.f, vz = 0.f;
    #pragma unroll
    for (int k = 0; k < KNBR; ++k) {
        float gg = G[(size_t)jreg[k] * HEADS + h];
        float ag = a[k] * gg;
        vx += ag * unitL[w][k][0];
        vy += ag * unitL[w][k][1];
        vz += ag * unitL[w][k][2];
    }
    float vn = sqrtf(vx * vx + vy * vy + vz * vz + 1e-8f);

    float4 o0 = {0.f, 0.f, 0.f, 0.f}, o1 = {0.f, 0.f, 0.f, 0.f};
    #pragma unroll
    for (int k = 0; k < KNBR; ++k) {
        const float4* vp = (const float4*)(QKV + (size_t)jreg[k] * 1536 + 1024 + lane * 8);
        float4 v0 = vp[0], v1 = vp[1];
        float ak = a[k];
        o0.x += ak * v0.x; o0.y += ak * v0.y; o0.z += ak * v0.z; o0.w += ak * v0.w;
        o1.x += ak * v1.x; o1.y += ak * v1.y; o1.z += ak * v1.z; o1.w += ak * v1.w;
    }

    float ov[8] = {o0.x, o0.y, o0.z, o0.w, o1.x, o1.y, o1.z, o1.w};
    half8 hi8, lo8;
    #pragma unroll
    for (int t = 0; t < 8; ++t) {
        _Float16 hi = (_Float16)ov[t];
        hi8[t] = hi;
        lo8[t] = (_Float16)(ov[t] - (float)hi);
    }
    *(half8*)(att2 + (size_t)n * 1152 + lane * 8) = hi8;
    *(half8*)(att2 + (size_t)n * 1152 + 576 + lane * 8) = lo8;
    if (c == 0) {
        _Float16 hi = (_Float16)vn, lo = (_Float16)(vn - (float)hi);
        att2[(size_t)n * 1152 + 512 + h] = hi;
        att2[(size_t)n * 1152 + 576 + 512 + h] = lo;
    }
    if (lane < 56) {
        att2[(size_t)n * 1152 + 520 + lane] = (_Float16)0.f;
        att2[(size_t)n * 1152 + 1096 + lane] = (_Float16)0.f;
    }
}

// ---------------------------------------------------------------------------
extern "C" void kernel_launch(void* const* d_in, const int* in_sizes, int n_in,
                              void* d_out, int out_size, void* d_ws, size_t ws_size,
                              hipStream_t stream) {
    const float* x      = (const float*)d_in[0];
    const float* coors  = (const float*)d_in[1];
    const int*   nbr    = (const int*)  d_in[2];
    const float* Wq     = (const float*)d_in[3];
    const float* Wk     = (const float*)d_in[4];
    const float* Wv     = (const float*)d_in[5];
    const float* w_gate = (const float*)d_in[6];
    const float* Wr1    = (const float*)d_in[7];
    const float* br1    = (const float*)d_in[8];
    const float* Wr2    = (const float*)d_in[9];
    const float* br2    = (const float*)d_in[10];
    const float* Wo     = (const float*)d_in[11];
    const float* alpha1 = (const float*)d_in[12];
    const float* gamma1 = (const float*)d_in[13];
    const float* beta1  = (const float*)d_in[14];
    const float* Wlin   = (const float*)d_in[15];
    const float* blin   = (const float*)d_in[16];
    const float* alpha2 = (const float*)d_in[17];
    const float* gamma2 = (const float*)d_in[18];
    const float* beta2  = (const float*)d_in[19];
    const float* Wout   = (const float*)d_in[20];
    const float* bout   = (const float*)d_in[21];
    const float* cb     = (const float*)d_in[22];

    char* wsb = (char*)d_ws;
    float*    QKV   = (float*)   (wsb + 0);          // 100.66 MB, dead after attn
    _Float16* att2  = (_Float16*)(wsb + 100663296);  // 37.75 MB, dead after Wo gemm
    _Float16* x2    = (_Float16*)(wsb + 138412032);  // 16.78 MB
    _Float16* wqkv2 = (_Float16*)(wsb + 155189248);  // 1664*512*2 = 1.70 MB
    _Float16* wo2   = (_Float16*)(wsb + 156893184);  // 256*1152*2 = 0.59 MB
    _Float16* wlin2 = (_Float16*)(wsb + 157483008);  // 512*512*2  = 0.52 MB
    _Float16* wout2 = (_Float16*)(wsb + 158007296);  // 64*1152*2  = 0.15 MB
    float*    G     = (float*)   (wsb + 158154752);  // 16384*8*4  = 0.52 MB
    float*    part  = (float*)   (wsb + 158679040);  // 256*4
    // aliases inside dead QKV region:
    _Float16* h1s   = (_Float16*)(wsb + 0);          // 16.78 MB (after attn)
    _Float16* h2s   = (_Float16*)(wsb + 20299776);   // 37.75 MB (after attn)

    float* outZ    = (float*)d_out;
    float* outLoss = outZ + (size_t)NPTS * OUTD;

    dim3 blk(256);

    // prep (x split + all weight splits + gate cols)
    prep<<<dim3(2048), blk, 0, stream>>>(x, Wq, Wk, Wv, w_gate, Wo, Wlin, Wout,
                                         x2, wqkv2, wo2, wlin2, wout2);
    // QKV+gate = x @ [Wq|Wk|Wv|w_gate]
    gemm_split<0><<<dim3(13, 128), blk, 0, stream>>>(x2, wqkv2, 256, 12, QKV, 1536,
        nullptr, nullptr, nullptr, nullptr, nullptr, nullptr, nullptr, nullptr, G);
    // attention
    attn_kernel<<<dim3(NPTS / 4), blk, 0, stream>>>(QKV, G, coors, nbr, Wr1, br1, Wr2, br2, att2);
    // h1 = DynTanh1(x + att@Wo) -> split; also writes h2 tail cols (x[:, :20])
    gemm_split<1><<<dim3(2, 128), blk, 0, stream>>>(att2, wo2, 576, 27, h1s, 0,
        nullptr, x, alpha1, gamma1, beta1, alpha2, gamma2, beta2, h2s);
    // h2[:, :512] = DynTanh2(gelu(h1@Wlin + blin)) -> split
    gemm_split<2><<<dim3(4, 128), blk, 0, stream>>>(h1s, wlin2, 256, 12, h2s, 0,
        blin, nullptr, alpha2, gamma2, beta2, nullptr, nullptr, nullptr, nullptr);
    // z = tanh(gelu(h2@Wout + bout)) fused with VQ
    gemm_out_vq<<<dim3(256), blk, 0, stream>>>(h2s, wout2, bout, cb, outZ, part);
    vq_reduce<<<dim3(1), blk, 0, stream>>>(part, outLoss);
}

// Round 6
// 397.835 us; speedup vs baseline: 1.2254x; 1.0728x over previous
//
#include <hip/hip_runtime.h>
#include <hip/hip_bf16.h>
#include <stdint.h>

#define NPTS 16384
#define CDIM 256
#define HEADS 8
#define KNBR 8
#define HIDD 512
#define OUTD 64
#define NEMB 64
#define RHIDD 16

typedef _Float16 half8 __attribute__((ext_vector_type(8)));
typedef float f32x4 __attribute__((ext_vector_type(4)));

__device__ __forceinline__ float gelu_tanh(float v) {
    float v3 = v * v * v;
    return 0.5f * v * (1.0f + tanhf(0.79788456080286535588f * (v + 0.044715f * v3)));
}

__device__ __forceinline__ void gload16(const void* g, void* l) {
    __builtin_amdgcn_global_load_lds((const __attribute__((address_space(1))) void*)g,
                                     (__attribute__((address_space(3))) void*)l, 16, 0, 0);
}

// ---------------------------------------------------------------------------
// Split-fp16 MFMA GEMM, 128x128 tile, 4 waves, 16x16x32 f16 MFMA.
// 3-term (AhiBhi + AhiBlo + AloBhi) -> fp32-grade accuracy.
// NEW schedule: per 32-true-K chunk, stage hi|lo interleaved in one 128-B LDS
// row (A and B), ONE barrier pair, THREE MFMA passes off the same staging:
// 33% fewer staged bytes + barriers than the K'=3*Kpad expansion.
// LDS XOR-swizzle: read addr = row*128 + (byteoff ^ ((row&7)<<4)); the
// global source is pre-swizzled per lane (segment sl = (l&7)^(row&7), sl>=4
// selects the lo half) so global_load_lds's linear dest lands correctly.
// KT = Kpad/32.
// EPI 0: QKV+gate: cols<1536 -> fp32 QKV (ld 1536); cols 1536..1543 -> G[N,8]
// EPI 1: +res(x), DynTanh1 -> split h1s (stride 512); cols<64 also write the
//        h2 tail (x[:, :20] DynTanh2 + zero pad) into aux (=h2s, stride 1152)
// EPI 2: gelu(+bias) then DynTanh2 -> split h2s (stride 1152)
// ---------------------------------------------------------------------------
template <int EPI>
__launch_bounds__(256)
__global__ void gemm_split(const _Float16* __restrict__ A2, const _Float16* __restrict__ B2,
                           int Kpad, int KT,
                           void* __restrict__ Cout, int ldc,
                           const float* __restrict__ bias,
                           const float* __restrict__ res,
                           const float* __restrict__ alphap,
                           const float* __restrict__ gamma,
                           const float* __restrict__ beta,
                           const float* __restrict__ a2p,
                           const float* __restrict__ g2,
                           const float* __restrict__ b2,
                           void* __restrict__ aux) {
    __shared__ __align__(16) char lds[32768];

    const int tid = threadIdx.x;
    const int l = tid & 63, w = tid >> 6;
    const int g = l >> 4, r = l & 15;
    const int wr = w >> 1, wc = w & 1;
    const int m0 = blockIdx.y * 128;
    const int n0 = blockIdx.x * 128;
    const int ldA = 2 * Kpad;
    // staging source mapping (pre-swizzled, hi/lo interleave)
    const int srow = l >> 3;                       // row within 8-row chunk
    const int sl = (l & 7) ^ srow;                 // logical 16B segment
    const int scol = (sl & 3) * 8 + ((sl >= 4) ? Kpad : 0);
    const int swz = (l & 7) << 4;                  // ds_read byte XOR
    const int aBase = (wr * 64 + r) * 128;
    const int bBase = 16384 + (wc * 64 + r) * 128;
    const int koh = (g << 4) ^ swz;                // hi byteoff in 128-B row
    const int kol = (64 | (g << 4)) ^ swz;         // lo byteoff

    f32x4 acc[4][4] = {};

    const _Float16* aS = A2 + (size_t)m0 * ldA + scol;
    const _Float16* bS = B2 + (size_t)n0 * ldA + scol;

    for (int t = 0; t < KT; ++t) {
        const int kk = t * 32;
        #pragma unroll
        for (int cc = 0; cc < 4; ++cc) {
            int ch = w * 4 + cc;                   // 1KB chunk id (wave-uniform)
            int row = ch * 8 + srow;
            gload16(aS + (size_t)row * ldA + kk, lds + ch * 1024);
            gload16(bS + (size_t)row * ldA + kk, lds + 16384 + ch * 1024);
        }
        __syncthreads();
        half8 ah[4], bh[4], xf[4];
        #pragma unroll
        for (int i = 0; i < 4; ++i) ah[i] = *(const half8*)(lds + aBase + i * 2048 + koh);
        #pragma unroll
        for (int j = 0; j < 4; ++j) bh[j] = *(const half8*)(lds + bBase + j * 2048 + koh);
        // pass 0: Ahi * Bhi
        #pragma unroll
        for (int i = 0; i < 4; ++i)
            #pragma unroll
            for (int j = 0; j < 4; ++j)
                acc[i][j] = __builtin_amdgcn_mfma_f32_16x16x32_f16(ah[i], bh[j], acc[i][j], 0, 0, 0);
        // pass 1: Ahi * Blo
        #pragma unroll
        for (int j = 0; j < 4; ++j) xf[j] = *(const half8*)(lds + bBase + j * 2048 + kol);
        #pragma unroll
        for (int i = 0; i < 4; ++i)
            #pragma unroll
            for (int j = 0; j < 4; ++j)
                acc[i][j] = __builtin_amdgcn_mfma_f32_16x16x32_f16(ah[i], xf[j], acc[i][j], 0, 0, 0);
        // pass 2: Alo * Bhi
        #pragma unroll
        for (int i = 0; i < 4; ++i) xf[i] = *(const half8*)(lds + aBase + i * 2048 + kol);
        #pragma unroll
        for (int i = 0; i < 4; ++i)
            #pragma unroll
            for (int j = 0; j < 4; ++j)
                acc[i][j] = __builtin_amdgcn_mfma_f32_16x16x32_f16(xf[i], bh[j], acc[i][j], 0, 0, 0);
        __syncthreads();
    }

    const float alp = (EPI == 1 || EPI == 2) ? alphap[0] : 0.f;
    #pragma unroll
    for (int i = 0; i < 4; ++i) {
        #pragma unroll
        for (int j = 0; j < 4; ++j) {
            const int gcol = n0 + wc * 64 + j * 16 + r;
            #pragma unroll
            for (int q = 0; q < 4; ++q) {
                const int row = m0 + wr * 64 + i * 16 + g * 4 + q;
                float v = acc[i][j][q];
                if (EPI == 0) {
                    if (gcol < 1536) {
                        ((float*)Cout)[(size_t)row * 1536 + gcol] = v;
                    } else if (gcol < 1544) {
                        ((float*)aux)[(size_t)row * 8 + (gcol - 1536)] = v;
                    }
                } else if (EPI == 1) {
                    v += res[(size_t)row * CDIM + gcol];
                    v = tanhf(alp * v) * gamma[gcol] + beta[gcol];
                    _Float16 hi = (_Float16)v;
                    _Float16 lo = (_Float16)(v - (float)hi);
                    _Float16* H = (_Float16*)Cout;
                    H[(size_t)row * 512 + gcol] = hi;
                    H[(size_t)row * 512 + 256 + gcol] = lo;
                    if (gcol < 64) {
                        int tc = 512 + gcol;
                        float tv = 0.f;
                        if (gcol < 20)
                            tv = tanhf(a2p[0] * res[(size_t)row * CDIM + gcol]) * g2[tc] + b2[tc];
                        _Float16 thi = (_Float16)tv;
                        _Float16 tlo = (_Float16)(tv - (float)thi);
                        _Float16* T = (_Float16*)aux;
                        T[(size_t)row * 1152 + tc] = thi;
                        T[(size_t)row * 1152 + 576 + tc] = tlo;
                    }
                } else if (EPI == 2) {
                    v = gelu_tanh(v + bias[gcol]);
                    v = tanhf(alp * v) * gamma[gcol] + beta[gcol];
                    _Float16 hi = (_Float16)v;
                    _Float16 lo = (_Float16)(v - (float)hi);
                    _Float16* H = (_Float16*)Cout;
                    H[(size_t)row * 1152 + gcol] = hi;
                    H[(size_t)row * 1152 + 576 + gcol] = lo;
                }
            }
        }
    }
}

// ---------------------------------------------------------------------------
// Wout GEMM (64x64 tile, 256 blocks) with fused VQ, same 3-pass chunk schedule.
// ---------------------------------------------------------------------------
__launch_bounds__(256)
__global__ void gemm_out_vq(const _Float16* __restrict__ A2, const _Float16* __restrict__ B2,
                            const float* __restrict__ bout, const float* __restrict__ cb,
                            float* __restrict__ outZ, float* __restrict__ partials) {
    __shared__ __align__(16) char lds[34816];   // 16KB staging, then zL|cbL
    __shared__ float psum[64];
    float* zL  = (float*)lds;                   // [64][68]
    float* cbL = (float*)(lds + 17408);         // [64][68], col 64 = ||cb||^2

    const int tid = threadIdx.x;
    const int l = tid & 63, w = tid >> 6;
    const int g = l >> 4, r = l & 15;
    const int wr = w >> 1, wc = w & 1;
    const int m0 = blockIdx.x * 64;
    const int Kpad = 576;
    const int ldA = 1152;
    const int srow = l >> 3;
    const int sl = (l & 7) ^ srow;
    const int scol = (sl & 3) * 8 + ((sl >= 4) ? Kpad : 0);
    const int swz = (l & 7) << 4;
    const int aBase = (wr * 32 + r) * 128;
    const int bBase = 8192 + (wc * 32 + r) * 128;
    const int koh = (g << 4) ^ swz;
    const int kol = (64 | (g << 4)) ^ swz;

    f32x4 acc[2][2] = {};

    const _Float16* aS = A2 + (size_t)m0 * ldA + scol;
    const _Float16* bS = B2 + scol;

    for (int t = 0; t < 18; ++t) {
        const int kk = t * 32;
        #pragma unroll
        for (int cc = 0; cc < 2; ++cc) {
            int ch = w * 2 + cc;
            int row = ch * 8 + srow;
            gload16(aS + (size_t)row * ldA + kk, lds + ch * 1024);
            gload16(bS + (size_t)row * ldA + kk, lds + 8192 + ch * 1024);
        }
        __syncthreads();
        half8 ah[2], bh[2], xf[2];
        #pragma unroll
        for (int i = 0; i < 2; ++i) ah[i] = *(const half8*)(lds + aBase + i * 2048 + koh);
        #pragma unroll
        for (int j = 0; j < 2; ++j) bh[j] = *(const half8*)(lds + bBase + j * 2048 + koh);
        #pragma unroll
        for (int i = 0; i < 2; ++i)
            #pragma unroll
            for (int j = 0; j < 2; ++j)
                acc[i][j] = __builtin_amdgcn_mfma_f32_16x16x32_f16(ah[i], bh[j], acc[i][j], 0, 0, 0);
        #pragma unroll
        for (int j = 0; j < 2; ++j) xf[j] = *(const half8*)(lds + bBase + j * 2048 + kol);
        #pragma unroll
        for (int i = 0; i < 2; ++i)
            #pragma unroll
            for (int j = 0; j < 2; ++j)
                acc[i][j] = __builtin_amdgcn_mfma_f32_16x16x32_f16(ah[i], xf[j], acc[i][j], 0, 0, 0);
        #pragma unroll
        for (int i = 0; i < 2; ++i) xf[i] = *(const half8*)(lds + aBase + i * 2048 + kol);
        #pragma unroll
        for (int i = 0; i < 2; ++i)
            #pragma unroll
            for (int j = 0; j < 2; ++j)
                acc[i][j] = __builtin_amdgcn_mfma_f32_16x16x32_f16(xf[i], bh[j], acc[i][j], 0, 0, 0);
        __syncthreads();
    }

    // z -> zL (staging region is dead now)
    #pragma unroll
    for (int i = 0; i < 2; ++i) {
        #pragma unroll
        for (int j = 0; j < 2; ++j) {
            int col = wc * 32 + j * 16 + r;
            #pragma unroll
            for (int q = 0; q < 4; ++q) {
                int rl = wr * 32 + i * 16 + g * 4 + q;
                zL[rl * 68 + col] = tanhf(gelu_tanh(acc[i][j][q] + bout[col]));
            }
        }
    }
    // stage codebook
    for (int i = tid; i < NEMB * OUTD / 4; i += 256) {
        float4 v = ((const float4*)cb)[i];
        int e = (i * 4) >> 6, c0 = (i * 4) & 63;
        cbL[e * 68 + c0 + 0] = v.x; cbL[e * 68 + c0 + 1] = v.y;
        cbL[e * 68 + c0 + 2] = v.z; cbL[e * 68 + c0 + 3] = v.w;
    }
    __syncthreads();
    if (tid < 64) {
        float cc = 0.f;
        #pragma unroll
        for (int d = 0; d < 64; ++d) { float cv = cbL[tid * 68 + d]; cc += cv * cv; }
        cbL[tid * 68 + 64] = cc;
    }
    __syncthreads();

    const int row = tid >> 2, part = tid & 3;
    float best = 1e30f;
    int bidx = 0;
    for (int e = part * 16; e < part * 16 + 16; ++e) {
        float dot = 0.f;
        #pragma unroll
        for (int d = 0; d < 64; ++d) dot += zL[row * 68 + d] * cbL[e * 68 + d];
        float sc = cbL[e * 68 + 64] - 2.f * dot;
        if (sc < best) { best = sc; bidx = e; }
    }
    #pragma unroll
    for (int m = 1; m <= 2; m <<= 1) {
        float ob = __shfl_xor(best, m, 64);
        int oi = __shfl_xor(bidx, m, 64);
        if (ob < best || (ob == best && oi < bidx)) { best = ob; bidx = oi; }
    }
    const int grow = m0 + row;
    float lsum = 0.f;
    #pragma unroll
    for (int u = 0; u < 16; ++u) {
        float cv = cbL[bidx * 68 + part * 16 + u];
        outZ[(size_t)grow * 64 + part * 16 + u] = cv;
        float df = zL[row * 68 + part * 16 + u] - cv;
        lsum += df * df;
    }
    lsum += __shfl_xor(lsum, 1, 64);
    lsum += __shfl_xor(lsum, 2, 64);
    if (part == 0) psum[row] = lsum;
    __syncthreads();
    if (tid < 64) {
        float v = psum[tid];
        #pragma unroll
        for (int m = 1; m < 64; m <<= 1) v += __shfl_xor(v, m, 64);
        if (tid == 0) partials[blockIdx.x] = v;
    }
}

__global__ void vq_reduce(const float* __restrict__ partials, float* __restrict__ out) {
    __shared__ float s[256];
    int tid = threadIdx.x;
    s[tid] = partials[tid];
    __syncthreads();
    for (int st = 128; st > 0; st >>= 1) {
        if (tid < st) s[tid] += s[tid + st];
        __syncthreads();
    }
    if (tid == 0) out[0] = 0.25f * s[0] / ((float)NPTS * (float)OUTD);
}

// ---------------------------------------------------------------------------
// merged prep: x2 split, wqkv2 (incl gate cols + zero pad), wo2T, wlin2T, wout2T
// ---------------------------------------------------------------------------
#define R0 (NPTS * CDIM)
#define S1 (1664 * 256)
#define S2 (256 * 576)
#define S3 (512 * 256)
#define S4 (64 * 576)
__global__ void prep(const float* __restrict__ x,
                     const float* __restrict__ Wq, const float* __restrict__ Wk,
                     const float* __restrict__ Wv, const float* __restrict__ w_gate,
                     const float* __restrict__ Wo, const float* __restrict__ Wlin,
                     const float* __restrict__ Wout,
                     _Float16* __restrict__ x2, _Float16* __restrict__ wqkv2,
                     _Float16* __restrict__ wo2, _Float16* __restrict__ wlin2,
                     _Float16* __restrict__ wout2) {
    for (int idx = blockIdx.x * 256 + threadIdx.x; idx < R0 + S1 + S2 + S3 + S4;
         idx += gridDim.x * 256) {
        float v; _Float16* dst; size_t o0, o1;
        if (idx < R0) {
            int n = idx >> 8, cc = idx & 255;
            v = x[idx];
            dst = x2; o0 = (size_t)n * 512 + cc; o1 = o0 + 256;
        } else if (idx < R0 + S1) {
            int t = idx - R0;
            int j = t >> 8, k = t & 255;
            if (j < 1536) {
                int jm = j & 511;
                const float* W = (j < 512) ? Wq : (j < 1024) ? Wk : Wv;
                v = W[(size_t)k * 512 + jm];
            } else if (j < 1544) {
                v = w_gate[(size_t)k * 8 + (j - 1536)];
            } else {
                v = 0.f;
            }
            dst = wqkv2; o0 = (size_t)j * 512 + k; o1 = o0 + 256;
        } else if (idx < R0 + S1 + S2) {
            int t = idx - R0 - S1;
            int j = t / 576, k = t - j * 576;
            v = (k < 520) ? Wo[(size_t)k * 256 + j] : 0.f;
            dst = wo2; o0 = (size_t)j * 1152 + k; o1 = o0 + 576;
        } else if (idx < R0 + S1 + S2 + S3) {
            int t = idx - R0 - S1 - S2;
            int j = t >> 8, k = t & 255;
            v = Wlin[(size_t)k * 512 + j];
            dst = wlin2; o0 = (size_t)j * 512 + k; o1 = o0 + 256;
        } else {
            int t = idx - R0 - S1 - S2 - S3;
            int j = t / 576, k = t - j * 576;
            v = (k < 532) ? Wout[(size_t)k * 64 + j] : 0.f;
            dst = wout2; o0 = (size_t)j * 1152 + k; o1 = o0 + 576;
        }
        _Float16 hi = (_Float16)v, lo = (_Float16)(v - (float)hi);
        dst[o0] = hi; dst[o1] = lo;
    }
}

// ---------------------------------------------------------------------------
// Attention (measured-best form, unchanged): one wave per node, lane = h*8+c.
// ---------------------------------------------------------------------------
__launch_bounds__(256)
__global__ void attn_kernel(const float* __restrict__ QKV, const float* __restrict__ G,
                            const float* __restrict__ coors, const int* __restrict__ nbr,
                            const float* __restrict__ Wr1, const float* __restrict__ br1,
                            const float* __restrict__ Wr2, const float* __restrict__ br2,
                            _Float16* __restrict__ att2) {
    __shared__ float unitL[4][8][3];
    __shared__ float distL[4][8];
    __shared__ float radH[4][8][16];

    const int tid = threadIdx.x;
    const int w = tid >> 6;
    const int lane = tid & 63;
    const int n = blockIdx.x * 4 + w;
    const int h = lane >> 3;
    const int c = lane & 7;

    int jreg[KNBR];
    #pragma unroll
    for (int k = 0; k < KNBR; ++k) jreg[k] = nbr[(size_t)n * KNBR + k];

    if (lane < KNBR) {
        int jj = jreg[lane];
        float rx = coors[(size_t)jj * 3 + 0] - coors[(size_t)n * 3 + 0];
        float ry = coors[(size_t)jj * 3 + 1] - coors[(size_t)n * 3 + 1];
        float rz = coors[(size_t)jj * 3 + 2] - coors[(size_t)n * 3 + 2];
        float d = sqrtf(rx * rx + ry * ry + rz * rz + 1e-8f);
        float inv = 1.0f / d;
        distL[w][lane] = d;
        unitL[w][lane][0] = rx * inv;
        unitL[w][lane][1] = ry * inv;
        unitL[w][lane][2] = rz * inv;
    }

    const float4* qp = (const float4*)(QKV + (size_t)n * 1536 + lane * 8);
    float4 q0 = qp[0], q1 = qp[1];
    float p[KNBR];
    #pragma unroll
    for (int k = 0; k < KNBR; ++k) {
        const float4* kp = (const float4*)(QKV + (size_t)jreg[k] * 1536 + 512 + lane * 8);
        float4 k0 = kp[0], k1 = kp[1];
        p[k] = q0.x * k0.x + q0.y * k0.y + q0.z * k0.z + q0.w * k0.w
             + q1.x * k1.x + q1.y * k1.y + q1.z * k1.z + q1.w * k1.w;
    }
    #pragma unroll
    for (int m = 1; m <= 4; m <<= 1) {
        #pragma unroll
        for (int k = 0; k < KNBR; ++k) p[k] += __shfl_xor(p[k], m, 64);
    }
    __syncthreads();

    #pragma unroll
    for (int rr = 0; rr < 2; ++rr) {
        int idx = lane + rr * 64;
        int k = idx >> 4, i = idx & 15;
        float hv = distL[w][k] * Wr1[i] + br1[i];
        radH[w][k][i] = gelu_tanh(hv);
    }
    __syncthreads();

    float lg[KNBR];
    float b2v = br2[h];
    #pragma unroll
    for (int k = 0; k < KNBR; ++k) {
        float rad = b2v;
        #pragma unroll
        for (int i = 0; i < RHIDD; ++i) rad += radH[w][k][i] * Wr2[i * HEADS + h];
        lg[k] = p[k] * 0.125f + rad;
        if (!(distL[w][k] <= 10.0f)) lg[k] = -1e9f;
    }
    float mx = lg[0];
    #pragma unroll
    for (int k = 1; k < KNBR; ++k) mx = fmaxf(mx, lg[k]);
    float a[KNBR];
    float s = 0.f;
    #pragma unroll
    for (int k = 0; k < KNBR; ++k) { a[k] = expf(lg[k] - mx); s += a[k]; }
    float is = 1.0f / s;
    #pragma unroll
    for (int k = 0; k < KNBR; ++k) a[k] *= is;

    float vx = 0.f, vy = 0.f, vz = 0.f;
    #pragma unroll
    for (int k = 0; k < KNBR; ++k) {
        float gg = G[(size_t)jreg[k] * HEADS + h];
        float ag = a[k] * gg;
        vx += ag * unitL[w][k][0];
        vy += ag * unitL[w][k][1];
        vz += ag * unitL[w][k][2];
    }
    float vn = sqrtf(vx * vx + vy * vy + vz * vz + 1e-8f);

    float4 o0 = {0.f, 0.f, 0.f, 0.f}, o1 = {0.f, 0.f, 0.f, 0.f};
    #pragma unroll
    for (int k = 0; k < KNBR; ++k) {
        const float4* vp = (const float4*)(QKV + (size_t)jreg[k] * 1536 + 1024 + lane * 8);
        float4 v0 = vp[0], v1 = vp[1];
        float ak = a[k];
        o0.x += ak * v0.x; o0.y += ak * v0.y; o0.z += ak * v0.z; o0.w += ak * v0.w;
        o1.x += ak * v1.x; o1.y += ak * v1.y; o1.z += ak * v1.z; o1.w += ak * v1.w;
    }

    float ov[8] = {o0.x, o0.y, o0.z, o0.w, o1.x, o1.y, o1.z, o1.w};
    half8 hi8, lo8;
    #pragma unroll
    for (int t = 0; t < 8; ++t) {
        _Float16 hi = (_Float16)ov[t];
        hi8[t] = hi;
        lo8[t] = (_Float16)(ov[t] - (float)hi);
    }
    *(half8*)(att2 + (size_t)n * 1152 + lane * 8) = hi8;
    *(half8*)(att2 + (size_t)n * 1152 + 576 + lane * 8) = lo8;
    if (c == 0) {
        _Float16 hi = (_Float16)vn, lo = (_Float16)(vn - (float)hi);
        att2[(size_t)n * 1152 + 512 + h] = hi;
        att2[(size_t)n * 1152 + 576 + 512 + h] = lo;
    }
    if (lane < 56) {
        att2[(size_t)n * 1152 + 520 + lane] = (_Float16)0.f;
        att2[(size_t)n * 1152 + 1096 + lane] = (_Float16)0.f;
    }
}

// ---------------------------------------------------------------------------
extern "C" void kernel_launch(void* const* d_in, const int* in_sizes, int n_in,
                              void* d_out, int out_size, void* d_ws, size_t ws_size,
                              hipStream_t stream) {
    const float* x      = (const float*)d_in[0];
    const float* coors  = (const float*)d_in[1];
    const int*   nbr    = (const int*)  d_in[2];
    const float* Wq     = (const float*)d_in[3];
    const float* Wk     = (const float*)d_in[4];
    const float* Wv     = (const float*)d_in[5];
    const float* w_gate = (const float*)d_in[6];
    const float* Wr1    = (const float*)d_in[7];
    const float* br1    = (const float*)d_in[8];
    const float* Wr2    = (const float*)d_in[9];
    const float* br2    = (const float*)d_in[10];
    const float* Wo     = (const float*)d_in[11];
    const float* alpha1 = (const float*)d_in[12];
    const float* gamma1 = (const float*)d_in[13];
    const float* beta1  = (const float*)d_in[14];
    const float* Wlin   = (const float*)d_in[15];
    const float* blin   = (const float*)d_in[16];
    const float* alpha2 = (const float*)d_in[17];
    const float* gamma2 = (const float*)d_in[18];
    const float* beta2  = (const float*)d_in[19];
    const float* Wout   = (const float*)d_in[20];
    const float* bout   = (const float*)d_in[21];
    const float* cb     = (const float*)d_in[22];

    char* wsb = (char*)d_ws;
    float*    QKV   = (float*)   (wsb + 0);          // 100.66 MB, dead after attn
    _Float16* att2  = (_Float16*)(wsb + 100663296);  // 37.75 MB, dead after Wo gemm
    _Float16* x2    = (_Float16*)(wsb + 138412032);  // 16.78 MB
    _Float16* wqkv2 = (_Float16*)(wsb + 155189248);  // 1664*512*2 = 1.70 MB
    _Float16* wo2   = (_Float16*)(wsb + 156893184);  // 256*1152*2 = 0.59 MB
    _Float16* wlin2 = (_Float16*)(wsb + 157483008);  // 512*512*2  = 0.52 MB
    _Float16* wout2 = (_Float16*)(wsb + 158007296);  // 64*1152*2  = 0.15 MB
    float*    G     = (float*)   (wsb + 158154752);  // 16384*8*4  = 0.52 MB
    float*    part  = (float*)   (wsb + 158679040);  // 256*4
    // aliases inside dead QKV region:
    _Float16* h1s   = (_Float16*)(wsb + 0);          // 16.78 MB (after attn)
    _Float16* h2s   = (_Float16*)(wsb + 20299776);   // 37.75 MB (after attn)

    float* outZ    = (float*)d_out;
    float* outLoss = outZ + (size_t)NPTS * OUTD;

    dim3 blk(256);

    // prep (x split + all weight splits + gate cols)
    prep<<<dim3(2048), blk, 0, stream>>>(x, Wq, Wk, Wv, w_gate, Wo, Wlin, Wout,
                                         x2, wqkv2, wo2, wlin2, wout2);
    // QKV+gate = x @ [Wq|Wk|Wv|w_gate]   (KT = 256/32 = 8)
    gemm_split<0><<<dim3(13, 128), blk, 0, stream>>>(x2, wqkv2, 256, 8, QKV, 1536,
        nullptr, nullptr, nullptr, nullptr, nullptr, nullptr, nullptr, nullptr, G);
    // attention
    attn_kernel<<<dim3(NPTS / 4), blk, 0, stream>>>(QKV, G, coors, nbr, Wr1, br1, Wr2, br2, att2);
    // h1 = DynTanh1(x + att@Wo) -> split; also writes h2 tail cols (KT = 576/32 = 18)
    gemm_split<1><<<dim3(2, 128), blk, 0, stream>>>(att2, wo2, 576, 18, h1s, 0,
        nullptr, x, alpha1, gamma1, beta1, alpha2, gamma2, beta2, h2s);
    // h2[:, :512] = DynTanh2(gelu(h1@Wlin + blin)) -> split (KT = 8)
    gemm_split<2><<<dim3(4, 128), blk, 0, stream>>>(h1s, wlin2, 256, 8, h2s, 0,
        blin, nullptr, alpha2, gamma2, beta2, nullptr, nullptr, nullptr, nullptr);
    // z = tanh(gelu(h2@Wout + bout)) fused with VQ
    gemm_out_vq<<<dim3(256), blk, 0, stream>>>(h2s, wout2, bout, cb, outZ, part);
    vq_reduce<<<dim3(1), blk, 0, stream>>>(part, outLoss);
}

// Round 7
// 379.866 us; speedup vs baseline: 1.2834x; 1.0473x over previous
//
#include <hip/hip_runtime.h>
#include <hip/hip_bf16.h>
#include <stdint.h>

#define NPTS 16384
#define CDIM 256
#define HEADS 8
#define KNBR 8
#define HIDD 512
#define OUTD 64
#define NEMB 64
#define RHIDD 16

typedef _Float16 half8 __attribute__((ext_vector_type(8)));
typedef float f32x4 __attribute__((ext_vector_type(4)));

__device__ __forceinline__ float gelu_tanh(float v) {
    float v3 = v * v * v;
    return 0.5f * v * (1.0f + tanhf(0.79788456080286535588f * (v + 0.044715f * v3)));
}

__device__ __forceinline__ void gload16(const void* g, void* l) {
    __builtin_amdgcn_global_load_lds((const __attribute__((address_space(1))) void*)g,
                                     (__attribute__((address_space(3))) void*)l, 16, 0, 0);
}

// ---------------------------------------------------------------------------
// Split-fp16 MFMA GEMM, 128x128 tile, 4 waves, 16x16x32 f16 MFMA.
// 3-term (AhiBhi + AhiBlo + AloBhi); per 32-true-K chunk hi|lo staged
// interleaved in one 128-B LDS row, one barrier pair, three MFMA passes.
// DBUF=1: double-buffered LDS (2x32KB) + counted vmcnt(8) (never drains the
// prefetch) + raw s_barrier — for small grids (1-2 blocks/CU) where there is
// no inter-block overlap to hide staging latency. DBUF=0: measured-best
// single-buffer form (QKV, 6.5 blocks/CU, implicit overlap already works).
// EPI 0: QKV+gate: cols<1536 -> fp32 QKV (ld 1536); cols 1536..1543 -> G[N,8]
// EPI 1: +res(x), DynTanh1 -> split h1s (stride 512); cols<64 also write the
//        h2 tail (x[:, :20] DynTanh2 + zero pad) into aux (=h2s, stride 1152)
// EPI 2: gelu(+bias) then DynTanh2 -> split h2s (stride 1152)
// ---------------------------------------------------------------------------
template <int EPI, int DBUF>
__launch_bounds__(256)
__global__ void gemm_split(const _Float16* __restrict__ A2, const _Float16* __restrict__ B2,
                           int Kpad, int KT,
                           void* __restrict__ Cout, int ldc,
                           const float* __restrict__ bias,
                           const float* __restrict__ res,
                           const float* __restrict__ alphap,
                           const float* __restrict__ gamma,
                           const float* __restrict__ beta,
                           const float* __restrict__ a2p,
                           const float* __restrict__ g2,
                           const float* __restrict__ b2,
                           void* __restrict__ aux) {
    constexpr int LBYTES = DBUF ? 65536 : 32768;
    __shared__ __align__(16) char lds[LBYTES];

    const int tid = threadIdx.x;
    const int l = tid & 63, w = tid >> 6;
    const int g = l >> 4, r = l & 15;
    const int wr = w >> 1, wc = w & 1;
    const int m0 = blockIdx.y * 128;
    const int n0 = blockIdx.x * 128;
    const int ldA = 2 * Kpad;
    const int srow = l >> 3;
    const int sl = (l & 7) ^ srow;
    const int scol = (sl & 3) * 8 + ((sl >= 4) ? Kpad : 0);
    const int swz = (l & 7) << 4;
    const int aBase = (wr * 64 + r) * 128;
    const int bBase = 16384 + (wc * 64 + r) * 128;
    const int koh = (g << 4) ^ swz;
    const int kol = (64 | (g << 4)) ^ swz;

    f32x4 acc[4][4] = {};

    const _Float16* aS = A2 + (size_t)m0 * ldA + scol;
    const _Float16* bS = B2 + (size_t)n0 * ldA + scol;

    auto stage = [&](int buf, int t) {
        const int kk = t * 32;
        char* d0 = lds + buf * 32768;
        #pragma unroll
        for (int cc = 0; cc < 4; ++cc) {
            int ch = w * 4 + cc;
            int row = ch * 8 + srow;
            gload16(aS + (size_t)row * ldA + kk, d0 + ch * 1024);
            gload16(bS + (size_t)row * ldA + kk, d0 + 16384 + ch * 1024);
        }
    };
    auto passes = [&](const char* Lb) {
        half8 ah[4], bh[4], xf[4];
        #pragma unroll
        for (int i = 0; i < 4; ++i) ah[i] = *(const half8*)(Lb + aBase + i * 2048 + koh);
        #pragma unroll
        for (int j = 0; j < 4; ++j) bh[j] = *(const half8*)(Lb + bBase + j * 2048 + koh);
        #pragma unroll
        for (int i = 0; i < 4; ++i)
            #pragma unroll
            for (int j = 0; j < 4; ++j)
                acc[i][j] = __builtin_amdgcn_mfma_f32_16x16x32_f16(ah[i], bh[j], acc[i][j], 0, 0, 0);
        #pragma unroll
        for (int j = 0; j < 4; ++j) xf[j] = *(const half8*)(Lb + bBase + j * 2048 + kol);
        #pragma unroll
        for (int i = 0; i < 4; ++i)
            #pragma unroll
            for (int j = 0; j < 4; ++j)
                acc[i][j] = __builtin_amdgcn_mfma_f32_16x16x32_f16(ah[i], xf[j], acc[i][j], 0, 0, 0);
        #pragma unroll
        for (int i = 0; i < 4; ++i) xf[i] = *(const half8*)(Lb + aBase + i * 2048 + kol);
        #pragma unroll
        for (int i = 0; i < 4; ++i)
            #pragma unroll
            for (int j = 0; j < 4; ++j)
                acc[i][j] = __builtin_amdgcn_mfma_f32_16x16x32_f16(xf[i], bh[j], acc[i][j], 0, 0, 0);
    };

    if (DBUF) {
        stage(0, 0);
        for (int t = 0; t < KT; ++t) {
            const int cur = t & 1;
            if (t + 1 < KT) {
                stage(cur ^ 1, t + 1);
                asm volatile("s_waitcnt vmcnt(8)" ::: "memory");
            } else {
                asm volatile("s_waitcnt vmcnt(0)" ::: "memory");
            }
            __builtin_amdgcn_s_barrier();
            __builtin_amdgcn_sched_barrier(0);
            passes(lds + cur * 32768);
            __builtin_amdgcn_s_barrier();   // buf[cur] reads done before t+2 overwrites
        }
    } else {
        for (int t = 0; t < KT; ++t) {
            stage(0, t);
            __syncthreads();
            passes(lds);
            __syncthreads();
        }
    }

    const float alp = (EPI == 1 || EPI == 2) ? alphap[0] : 0.f;
    #pragma unroll
    for (int i = 0; i < 4; ++i) {
        #pragma unroll
        for (int j = 0; j < 4; ++j) {
            const int gcol = n0 + wc * 64 + j * 16 + r;
            #pragma unroll
            for (int q = 0; q < 4; ++q) {
                const int row = m0 + wr * 64 + i * 16 + g * 4 + q;
                float v = acc[i][j][q];
                if (EPI == 0) {
                    if (gcol < 1536) {
                        ((float*)Cout)[(size_t)row * 1536 + gcol] = v;
                    } else if (gcol < 1544) {
                        ((float*)aux)[(size_t)row * 8 + (gcol - 1536)] = v;
                    }
                } else if (EPI == 1) {
                    v += res[(size_t)row * CDIM + gcol];
                    v = tanhf(alp * v) * gamma[gcol] + beta[gcol];
                    _Float16 hi = (_Float16)v;
                    _Float16 lo = (_Float16)(v - (float)hi);
                    _Float16* H = (_Float16*)Cout;
                    H[(size_t)row * 512 + gcol] = hi;
                    H[(size_t)row * 512 + 256 + gcol] = lo;
                    if (gcol < 64) {
                        int tc = 512 + gcol;
                        float tv = 0.f;
                        if (gcol < 20)
                            tv = tanhf(a2p[0] * res[(size_t)row * CDIM + gcol]) * g2[tc] + b2[tc];
                        _Float16 thi = (_Float16)tv;
                        _Float16 tlo = (_Float16)(tv - (float)thi);
                        _Float16* T = (_Float16*)aux;
                        T[(size_t)row * 1152 + tc] = thi;
                        T[(size_t)row * 1152 + 576 + tc] = tlo;
                    }
                } else if (EPI == 2) {
                    v = gelu_tanh(v + bias[gcol]);
                    v = tanhf(alp * v) * gamma[gcol] + beta[gcol];
                    _Float16 hi = (_Float16)v;
                    _Float16 lo = (_Float16)(v - (float)hi);
                    _Float16* H = (_Float16*)Cout;
                    H[(size_t)row * 1152 + gcol] = hi;
                    H[(size_t)row * 1152 + 576 + gcol] = lo;
                }
            }
        }
    }
}

// ---------------------------------------------------------------------------
// Wout GEMM (64x64 tile, 256 blocks = 1/CU) with fused VQ + fused loss
// reduction (one fp32 atomicAdd per block; outLoss zero-init'd in prep).
// Double-buffered staging (2x16KB) with counted vmcnt(4).
// ---------------------------------------------------------------------------
__launch_bounds__(256)
__global__ void gemm_out_vq(const _Float16* __restrict__ A2, const _Float16* __restrict__ B2,
                            const float* __restrict__ bout, const float* __restrict__ cb,
                            float* __restrict__ outZ, float* __restrict__ outLoss) {
    __shared__ __align__(16) char lds[34816];   // dbuf staging 32KB; then zL|cbL
    __shared__ float psum[64];
    float* zL  = (float*)lds;                   // [64][68]
    float* cbL = (float*)(lds + 17408);         // [64][68], col 64 = ||cb||^2

    const int tid = threadIdx.x;
    const int l = tid & 63, w = tid >> 6;
    const int g = l >> 4, r = l & 15;
    const int wr = w >> 1, wc = w & 1;
    const int m0 = blockIdx.x * 64;
    const int Kpad = 576;
    const int ldA = 1152;
    const int srow = l >> 3;
    const int sl = (l & 7) ^ srow;
    const int scol = (sl & 3) * 8 + ((sl >= 4) ? Kpad : 0);
    const int swz = (l & 7) << 4;
    const int aBase = (wr * 32 + r) * 128;
    const int bBase = 8192 + (wc * 32 + r) * 128;
    const int koh = (g << 4) ^ swz;
    const int kol = (64 | (g << 4)) ^ swz;

    f32x4 acc[2][2] = {};

    const _Float16* aS = A2 + (size_t)m0 * ldA + scol;
    const _Float16* bS = B2 + scol;

    auto stage = [&](int buf, int t) {
        const int kk = t * 32;
        char* d0 = lds + buf * 16384;
        #pragma unroll
        for (int cc = 0; cc < 2; ++cc) {
            int ch = w * 2 + cc;
            int row = ch * 8 + srow;
            gload16(aS + (size_t)row * ldA + kk, d0 + ch * 1024);
            gload16(bS + (size_t)row * ldA + kk, d0 + 8192 + ch * 1024);
        }
    };

    stage(0, 0);
    for (int t = 0; t < 18; ++t) {
        const int cur = t & 1;
        if (t + 1 < 18) {
            stage(cur ^ 1, t + 1);
            asm volatile("s_waitcnt vmcnt(4)" ::: "memory");
        } else {
            asm volatile("s_waitcnt vmcnt(0)" ::: "memory");
        }
        __builtin_amdgcn_s_barrier();
        __builtin_amdgcn_sched_barrier(0);
        const char* Lb = lds + cur * 16384;
        half8 ah[2], bh[2], xf[2];
        #pragma unroll
        for (int i = 0; i < 2; ++i) ah[i] = *(const half8*)(Lb + aBase + i * 2048 + koh);
        #pragma unroll
        for (int j = 0; j < 2; ++j) bh[j] = *(const half8*)(Lb + bBase + j * 2048 + koh);
        #pragma unroll
        for (int i = 0; i < 2; ++i)
            #pragma unroll
            for (int j = 0; j < 2; ++j)
                acc[i][j] = __builtin_amdgcn_mfma_f32_16x16x32_f16(ah[i], bh[j], acc[i][j], 0, 0, 0);
        #pragma unroll
        for (int j = 0; j < 2; ++j) xf[j] = *(const half8*)(Lb + bBase + j * 2048 + kol);
        #pragma unroll
        for (int i = 0; i < 2; ++i)
            #pragma unroll
            for (int j = 0; j < 2; ++j)
                acc[i][j] = __builtin_amdgcn_mfma_f32_16x16x32_f16(ah[i], xf[j], acc[i][j], 0, 0, 0);
        #pragma unroll
        for (int i = 0; i < 2; ++i) xf[i] = *(const half8*)(Lb + aBase + i * 2048 + kol);
        #pragma unroll
        for (int i = 0; i < 2; ++i)
            #pragma unroll
            for (int j = 0; j < 2; ++j)
                acc[i][j] = __builtin_amdgcn_mfma_f32_16x16x32_f16(xf[i], bh[j], acc[i][j], 0, 0, 0);
        __builtin_amdgcn_s_barrier();
    }

    // z -> zL (staging region dead now; last-iter barrier already passed)
    #pragma unroll
    for (int i = 0; i < 2; ++i) {
        #pragma unroll
        for (int j = 0; j < 2; ++j) {
            int col = wc * 32 + j * 16 + r;
            #pragma unroll
            for (int q = 0; q < 4; ++q) {
                int rl = wr * 32 + i * 16 + g * 4 + q;
                zL[rl * 68 + col] = tanhf(gelu_tanh(acc[i][j][q] + bout[col]));
            }
        }
    }
    // stage codebook
    for (int i = tid; i < NEMB * OUTD / 4; i += 256) {
        float4 v = ((const float4*)cb)[i];
        int e = (i * 4) >> 6, c0 = (i * 4) & 63;
        cbL[e * 68 + c0 + 0] = v.x; cbL[e * 68 + c0 + 1] = v.y;
        cbL[e * 68 + c0 + 2] = v.z; cbL[e * 68 + c0 + 3] = v.w;
    }
    __syncthreads();
    if (tid < 64) {
        float cc = 0.f;
        #pragma unroll
        for (int d = 0; d < 64; ++d) { float cv = cbL[tid * 68 + d]; cc += cv * cv; }
        cbL[tid * 68 + 64] = cc;
    }
    __syncthreads();

    const int row = tid >> 2, part = tid & 3;
    float best = 1e30f;
    int bidx = 0;
    for (int e = part * 16; e < part * 16 + 16; ++e) {
        float dot = 0.f;
        #pragma unroll
        for (int d = 0; d < 64; ++d) dot += zL[row * 68 + d] * cbL[e * 68 + d];
        float sc = cbL[e * 68 + 64] - 2.f * dot;
        if (sc < best) { best = sc; bidx = e; }
    }
    #pragma unroll
    for (int m = 1; m <= 2; m <<= 1) {
        float ob = __shfl_xor(best, m, 64);
        int oi = __shfl_xor(bidx, m, 64);
        if (ob < best || (ob == best && oi < bidx)) { best = ob; bidx = oi; }
    }
    const int grow = m0 + row;
    float lsum = 0.f;
    #pragma unroll
    for (int u = 0; u < 16; ++u) {
        float cv = cbL[bidx * 68 + part * 16 + u];
        outZ[(size_t)grow * 64 + part * 16 + u] = cv;
        float df = zL[row * 68 + part * 16 + u] - cv;
        lsum += df * df;
    }
    lsum += __shfl_xor(lsum, 1, 64);
    lsum += __shfl_xor(lsum, 2, 64);
    if (part == 0) psum[row] = lsum;
    __syncthreads();
    if (tid < 64) {
        float v = psum[tid];
        #pragma unroll
        for (int m = 1; m < 64; m <<= 1) v += __shfl_xor(v, m, 64);
        if (tid == 0)
            atomicAdd(outLoss, v * (0.25f / ((float)NPTS * (float)OUTD)));
    }
}

// ---------------------------------------------------------------------------
// merged prep: x2 split, wqkv2 (incl gate cols + zero pad), wo2T, wlin2T,
// wout2T; also zero-inits outLoss (d_out is re-poisoned before every launch)
// ---------------------------------------------------------------------------
#define R0 (NPTS * CDIM)
#define S1 (1664 * 256)
#define S2 (256 * 576)
#define S3 (512 * 256)
#define S4 (64 * 576)
__global__ void prep(const float* __restrict__ x,
                     const float* __restrict__ Wq, const float* __restrict__ Wk,
                     const float* __restrict__ Wv, const float* __restrict__ w_gate,
                     const float* __restrict__ Wo, const float* __restrict__ Wlin,
                     const float* __restrict__ Wout,
                     _Float16* __restrict__ x2, _Float16* __restrict__ wqkv2,
                     _Float16* __restrict__ wo2, _Float16* __restrict__ wlin2,
                     _Float16* __restrict__ wout2, float* __restrict__ outLoss) {
    if (blockIdx.x == 0 && threadIdx.x == 0) *outLoss = 0.f;
    for (int idx = blockIdx.x * 256 + threadIdx.x; idx < R0 + S1 + S2 + S3 + S4;
         idx += gridDim.x * 256) {
        float v; _Float16* dst; size_t o0, o1;
        if (idx < R0) {
            int n = idx >> 8, cc = idx & 255;
            v = x[idx];
            dst = x2; o0 = (size_t)n * 512 + cc; o1 = o0 + 256;
        } else if (idx < R0 + S1) {
            int t = idx - R0;
            int j = t >> 8, k = t & 255;
            if (j < 1536) {
                int jm = j & 511;
                const float* W = (j < 512) ? Wq : (j < 1024) ? Wk : Wv;
                v = W[(size_t)k * 512 + jm];
            } else if (j < 1544) {
                v = w_gate[(size_t)k * 8 + (j - 1536)];
            } else {
                v = 0.f;
            }
            dst = wqkv2; o0 = (size_t)j * 512 + k; o1 = o0 + 256;
        } else if (idx < R0 + S1 + S2) {
            int t = idx - R0 - S1;
            int j = t / 576, k = t - j * 576;
            v = (k < 520) ? Wo[(size_t)k * 256 + j] : 0.f;
            dst = wo2; o0 = (size_t)j * 1152 + k; o1 = o0 + 576;
        } else if (idx < R0 + S1 + S2 + S3) {
            int t = idx - R0 - S1 - S2;
            int j = t >> 8, k = t & 255;
            v = Wlin[(size_t)k * 512 + j];
            dst = wlin2; o0 = (size_t)j * 512 + k; o1 = o0 + 256;
        } else {
            int t = idx - R0 - S1 - S2 - S3;
            int j = t / 576, k = t - j * 576;
            v = (k < 532) ? Wout[(size_t)k * 64 + j] : 0.f;
            dst = wout2; o0 = (size_t)j * 1152 + k; o1 = o0 + 576;
        }
        _Float16 hi = (_Float16)v, lo = (_Float16)(v - (float)hi);
        dst[o0] = hi; dst[o1] = lo;
    }
}

// ---------------------------------------------------------------------------
// Attention (measured-best form, unchanged): one wave per node, lane = h*8+c.
// ---------------------------------------------------------------------------
__launch_bounds__(256)
__global__ void attn_kernel(const float* __restrict__ QKV, const float* __restrict__ G,
                            const float* __restrict__ coors, const int* __restrict__ nbr,
                            const float* __restrict__ Wr1, const float* __restrict__ br1,
                            const float* __restrict__ Wr2, const float* __restrict__ br2,
                            _Float16* __restrict__ att2) {
    __shared__ float unitL[4][8][3];
    __shared__ float distL[4][8];
    __shared__ float radH[4][8][16];

    const int tid = threadIdx.x;
    const int w = tid >> 6;
    const int lane = tid & 63;
    const int n = blockIdx.x * 4 + w;
    const int h = lane >> 3;
    const int c = lane & 7;

    int jreg[KNBR];
    #pragma unroll
    for (int k = 0; k < KNBR; ++k) jreg[k] = nbr[(size_t)n * KNBR + k];

    if (lane < KNBR) {
        int jj = jreg[lane];
        float rx = coors[(size_t)jj * 3 + 0] - coors[(size_t)n * 3 + 0];
        float ry = coors[(size_t)jj * 3 + 1] - coors[(size_t)n * 3 + 1];
        float rz = coors[(size_t)jj * 3 + 2] - coors[(size_t)n * 3 + 2];
        float d = sqrtf(rx * rx + ry * ry + rz * rz + 1e-8f);
        float inv = 1.0f / d;
        distL[w][lane] = d;
        unitL[w][lane][0] = rx * inv;
        unitL[w][lane][1] = ry * inv;
        unitL[w][lane][2] = rz * inv;
    }

    const float4* qp = (const float4*)(QKV + (size_t)n * 1536 + lane * 8);
    float4 q0 = qp[0], q1 = qp[1];
    float p[KNBR];
    #pragma unroll
    for (int k = 0; k < KNBR; ++k) {
        const float4* kp = (const float4*)(QKV + (size_t)jreg[k] * 1536 + 512 + lane * 8);
        float4 k0 = kp[0], k1 = kp[1];
        p[k] = q0.x * k0.x + q0.y * k0.y + q0.z * k0.z + q0.w * k0.w
             + q1.x * k1.x + q1.y * k1.y + q1.z * k1.z + q1.w * k1.w;
    }
    #pragma unroll
    for (int m = 1; m <= 4; m <<= 1) {
        #pragma unroll
        for (int k = 0; k < KNBR; ++k) p[k] += __shfl_xor(p[k], m, 64);
    }
    __syncthreads();

    #pragma unroll
    for (int rr = 0; rr < 2; ++rr) {
        int idx = lane + rr * 64;
        int k = idx >> 4, i = idx & 15;
        float hv = distL[w][k] * Wr1[i] + br1[i];
        radH[w][k][i] = gelu_tanh(hv);
    }
    __syncthreads();

    float lg[KNBR];
    float b2v = br2[h];
    #pragma unroll
    for (int k = 0; k < KNBR; ++k) {
        float rad = b2v;
        #pragma unroll
        for (int i = 0; i < RHIDD; ++i) rad += radH[w][k][i] * Wr2[i * HEADS + h];
        lg[k] = p[k] * 0.125f + rad;
        if (!(distL[w][k] <= 10.0f)) lg[k] = -1e9f;
    }
    float mx = lg[0];
    #pragma unroll
    for (int k = 1; k < KNBR; ++k) mx = fmaxf(mx, lg[k]);
    float a[KNBR];
    float s = 0.f;
    #pragma unroll
    for (int k = 0; k < KNBR; ++k) { a[k] = expf(lg[k] - mx); s += a[k]; }
    float is = 1.0f / s;
    #pragma unroll
    for (int k = 0; k < KNBR; ++k) a[k] *= is;

    float vx = 0.f, vy = 0.f, vz = 0.f;
    #pragma unroll
    for (int k = 0; k < KNBR; ++k) {
        float gg = G[(size_t)jreg[k] * HEADS + h];
        float ag = a[k] * gg;
        vx += ag * unitL[w][k][0];
        vy += ag * unitL[w][k][1];
        vz += ag * unitL[w][k][2];
    }
    float vn = sqrtf(vx * vx + vy * vy + vz * vz + 1e-8f);

    float4 o0 = {0.f, 0.f, 0.f, 0.f}, o1 = {0.f, 0.f, 0.f, 0.f};
    #pragma unroll
    for (int k = 0; k < KNBR; ++k) {
        const float4* vp = (const float4*)(QKV + (size_t)jreg[k] * 1536 + 1024 + lane * 8);
        float4 v0 = vp[0], v1 = vp[1];
        float ak = a[k];
        o0.x += ak * v0.x; o0.y += ak * v0.y; o0.z += ak * v0.z; o0.w += ak * v0.w;
        o1.x += ak * v1.x; o1.y += ak * v1.y; o1.z += ak * v1.z; o1.w += ak * v1.w;
    }

    float ov[8] = {o0.x, o0.y, o0.z, o0.w, o1.x, o1.y, o1.z, o1.w};
    half8 hi8, lo8;
    #pragma unroll
    for (int t = 0; t < 8; ++t) {
        _Float16 hi = (_Float16)ov[t];
        hi8[t] = hi;
        lo8[t] = (_Float16)(ov[t] - (float)hi);
    }
    *(half8*)(att2 + (size_t)n * 1152 + lane * 8) = hi8;
    *(half8*)(att2 + (size_t)n * 1152 + 576 + lane * 8) = lo8;
    if (c == 0) {
        _Float16 hi = (_Float16)vn, lo = (_Float16)(vn - (float)hi);
        att2[(size_t)n * 1152 + 512 + h] = hi;
        att2[(size_t)n * 1152 + 576 + 512 + h] = lo;
    }
    if (lane < 56) {
        att2[(size_t)n * 1152 + 520 + lane] = (_Float16)0.f;
        att2[(size_t)n * 1152 + 1096 + lane] = (_Float16)0.f;
    }
}

// ---------------------------------------------------------------------------
extern "C" void kernel_launch(void* const* d_in, const int* in_sizes, int n_in,
                              void* d_out, int out_size, void* d_ws, size_t ws_size,
                              hipStream_t stream) {
    const float* x      = (const float*)d_in[0];
    const float* coors  = (const float*)d_in[1];
    const int*   nbr    = (const int*)  d_in[2];
    const float* Wq     = (const float*)d_in[3];
    const float* Wk     = (const float*)d_in[4];
    const float* Wv     = (const float*)d_in[5];
    const float* w_gate = (const float*)d_in[6];
    const float* Wr1    = (const float*)d_in[7];
    const float* br1    = (const float*)d_in[8];
    const float* Wr2    = (const float*)d_in[9];
    const float* br2    = (const float*)d_in[10];
    const float* Wo     = (const float*)d_in[11];
    const float* alpha1 = (const float*)d_in[12];
    const float* gamma1 = (const float*)d_in[13];
    const float* beta1  = (const float*)d_in[14];
    const float* Wlin   = (const float*)d_in[15];
    const float* blin   = (const float*)d_in[16];
    const float* alpha2 = (const float*)d_in[17];
    const float* gamma2 = (const float*)d_in[18];
    const float* beta2  = (const float*)d_in[19];
    const float* Wout   = (const float*)d_in[20];
    const float* bout   = (const float*)d_in[21];
    const float* cb     = (const float*)d_in[22];

    char* wsb = (char*)d_ws;
    float*    QKV   = (float*)   (wsb + 0);          // 100.66 MB, dead after attn
    _Float16* att2  = (_Float16*)(wsb + 100663296);  // 37.75 MB, dead after Wo gemm
    _Float16* x2    = (_Float16*)(wsb + 138412032);  // 16.78 MB
    _Float16* wqkv2 = (_Float16*)(wsb + 155189248);  // 1664*512*2 = 1.70 MB
    _Float16* wo2   = (_Float16*)(wsb + 156893184);  // 256*1152*2 = 0.59 MB
    _Float16* wlin2 = (_Float16*)(wsb + 157483008);  // 512*512*2  = 0.52 MB
    _Float16* wout2 = (_Float16*)(wsb + 158007296);  // 64*1152*2  = 0.15 MB
    float*    G     = (float*)   (wsb + 158154752);  // 16384*8*4  = 0.52 MB
    // aliases inside dead QKV region:
    _Float16* h1s   = (_Float16*)(wsb + 0);          // 16.78 MB (after attn)
    _Float16* h2s   = (_Float16*)(wsb + 20299776);   // 37.75 MB (after attn)

    float* outZ    = (float*)d_out;
    float* outLoss = outZ + (size_t)NPTS * OUTD;

    dim3 blk(256);

    // prep (x split + all weight splits + gate cols + loss zero-init)
    prep<<<dim3(2048), blk, 0, stream>>>(x, Wq, Wk, Wv, w_gate, Wo, Wlin, Wout,
                                         x2, wqkv2, wo2, wlin2, wout2, outLoss);
    // QKV+gate = x @ [Wq|Wk|Wv|w_gate]   (KT = 8; single-buffer, 6.5 blocks/CU)
    gemm_split<0, 0><<<dim3(13, 128), blk, 0, stream>>>(x2, wqkv2, 256, 8, QKV, 1536,
        nullptr, nullptr, nullptr, nullptr, nullptr, nullptr, nullptr, nullptr, G);
    // attention
    attn_kernel<<<dim3(NPTS / 4), blk, 0, stream>>>(QKV, G, coors, nbr, Wr1, br1, Wr2, br2, att2);
    // h1 = DynTanh1(x + att@Wo) -> split (KT = 18; dbuf, 1 block/CU)
    gemm_split<1, 1><<<dim3(2, 128), blk, 0, stream>>>(att2, wo2, 576, 18, h1s, 0,
        nullptr, x, alpha1, gamma1, beta1, alpha2, gamma2, beta2, h2s);
    // h2[:, :512] = DynTanh2(gelu(h1@Wlin + blin)) -> split (KT = 8; dbuf, 2/CU)
    gemm_split<2, 1><<<dim3(4, 128), blk, 0, stream>>>(h1s, wlin2, 256, 8, h2s, 0,
        blin, nullptr, alpha2, gamma2, beta2, nullptr, nullptr, nullptr, nullptr);
    // z = tanh(gelu(h2@Wout + bout)) fused with VQ + loss atomic
    gemm_out_vq<<<dim3(256), blk, 0, stream>>>(h2s, wout2, bout, cb, outZ, outLoss);
}